// Round 3
// baseline (804.222 us; speedup 1.0000x reference)
//
#include <hip/hip_runtime.h>
#include <hip/hip_bf16.h>

#define O_NODES 50000
#define N_EDGES 200000
#define DD 256
#define KDIM 512
#define NDIM 512
#define ET 64           // edges per block (64 -> 67.6KB LDS -> 2 blocks/CU)
#define LDST 520        // padded bf16 LDS row stride

typedef __bf16 bf16x8 __attribute__((ext_vector_type(8)));
typedef float  f32x4  __attribute__((ext_vector_type(4)));
typedef short  s16x2  __attribute__((ext_vector_type(2)));
typedef __attribute__((address_space(1))) s16x2* gptr_s16x2;

__device__ __forceinline__ void atomic_pk_add_bf16(void* addr, float lo, float hi) {
#if __has_builtin(__builtin_amdgcn_global_atomic_fadd_v2bf16)
    __hip_bfloat16 l = __float2bfloat16(lo), h = __float2bfloat16(hi);
    s16x2 v;
    v.x = *(short*)&l;
    v.y = *(short*)&h;
    __builtin_amdgcn_global_atomic_fadd_v2bf16((gptr_s16x2)(unsigned long long)addr, v);
#else
    unsigned* a = (unsigned*)addr;
    unsigned old = *a, assumed;
    do {
        assumed = old;
        float olo = __uint_as_float((assumed & 0xffffu) << 16);
        float ohi = __uint_as_float(assumed & 0xffff0000u);
        __hip_bfloat16 nl = __float2bfloat16(olo + lo);
        __hip_bfloat16 nh = __float2bfloat16(ohi + hi);
        unsigned nv = (unsigned)*(unsigned short*)&nl | ((unsigned)*(unsigned short*)&nh << 16);
        old = atomicCAS(a, assumed, nv);
    } while (old != assumed);
#endif
}

__device__ __forceinline__ int get_pair(const int* __restrict__ p, long e, int which, int is32) {
    // is32: [sub0,obj0,...]; int64 case: [sub0,0,obj0,0,...] viewed as int32
    return is32 ? p[2 * e + which] : p[4 * e + 2 * which];
}

__device__ __forceinline__ float load_f(const void* p, long i, int is_f32) {
    if (is_f32) return ((const float*)p)[i];
    unsigned short u = ((const unsigned short*)p)[i];
    return __uint_as_float((unsigned)u << 16);
}

// flag[0] = pairs-are-int32, flag[1] = floats-are-f32
__global__ void init_misc(float* mbuf, int* flag) {
    int i = blockIdx.x * 256 + threadIdx.x;
    if (i < O_NODES) mbuf[i] = 10.0f;
    if (i == 0) { flag[0] = 0; }
}

__global__ void detect_fmt(const int* __restrict__ pairs, int* flag) {
    int i = blockIdx.x * 256 + threadIdx.x;   // 8192 probes
    if (pairs[2 * i + 1] != 0) flag[0] = 1;
}

__global__ void detect_dtype(const unsigned short* __restrict__ w, int* flag) {
    // bf16 data: low half of each 32b word is a bf16 N(0,1) draw -> |v| in [0.004,16] w.p. ~99%
    // f32 data: low half is mantissa noise -> in range w.p. ~4%
    int lane = threadIdx.x & 63;
    unsigned short u = w[2 * lane];
    float v = fabsf(__uint_as_float((unsigned)u << 16));
    bool in_range = (v > 0.004f && v < 16.0f);
    unsigned long long m = __ballot(in_range);
    if (lane == 0) flag[1] = (__popcll(m) < 32) ? 1 : 0;
}

__global__ void edge_max(const int* __restrict__ pairs, const void* __restrict__ conf,
                         float* mbuf, const int* __restrict__ flag) {
    int i = blockIdx.x * 256 + threadIdx.x;
    if (i >= N_EDGES) return;
    int is32 = flag[0], isf = flag[1];
    int s = get_pair(pairs, i, 0, is32);
    int o = get_pair(pairs, i, 1, is32);
    float c = load_f(conf, i, isf);
    int cb = __float_as_int(c);
    // mbuf init = 10.0f (positive) -> signed-int atomicMax is order-correct
    atomicMax((int*)&mbuf[s], cb);
    atomicMax((int*)&mbuf[o], cb);
}

__global__ void edge_denom(const int* __restrict__ pairs, const void* __restrict__ conf,
                           const float* __restrict__ mbuf, float* denom, const int* __restrict__ flag) {
    int i = blockIdx.x * 256 + threadIdx.x;
    if (i >= N_EDGES) return;
    int is32 = flag[0], isf = flag[1];
    int s = get_pair(pairs, i, 0, is32);
    int o = get_pair(pairs, i, 1, is32);
    float c = load_f(conf, i, isf);
    atomicAdd(&denom[s], __expf(c - mbuf[s]));
    atomicAdd(&denom[o], __expf(c - mbuf[o]));
}

// Pack W[k][n] (512x512 row-major) into MFMA-B-fragment order (bf16):
// bf16 flat idx ((tk*32+tn)*64 + lane)*8 + j holds B[tk*32 + (lane>>4)*8 + j][tn*16 + (lane&15)]
__global__ void repack_w(const void* __restrict__ W, __hip_bfloat16* __restrict__ Wp,
                         const int* __restrict__ flag) {
    int idx = blockIdx.x * 256 + threadIdx.x;  // < 262144
    int isf = flag[1];
    int j  = idx & 7;
    int l  = (idx >> 3) & 63;
    int tn = (idx >> 9) & 31;
    int tk = idx >> 14;
    int k = tk * 32 + (l >> 4) * 8 + j;
    int n = tn * 16 + (l & 15);
    Wp[idx] = __float2bfloat16(load_f(W, (long)k * NDIM + n, isf));
}

__global__ __launch_bounds__(256, 2) void fused_mlp(
    const void* __restrict__ objf,
    const int* __restrict__ pairs,
    const void* __restrict__ conf,
    const __hip_bfloat16* __restrict__ w1p,
    const void* __restrict__ b1,
    const __hip_bfloat16* __restrict__ w2p,
    const void* __restrict__ b2,
    const float* __restrict__ mbuf,
    __hip_bfloat16* __restrict__ numer,
    const int* __restrict__ flag)
{
    extern __shared__ char smem[];
    __hip_bfloat16* sA    = (__hip_bfloat16*)smem;                 // ET x LDST bf16
    int*            sNode = (int*)(smem + ET * LDST * 2);          // [2][ET]
    float*          sW    = (float*)(smem + ET * LDST * 2 + 2 * ET * 4); // [2][ET]

    const int tid  = threadIdx.x;
    const int wave = tid >> 6;      // 0..3
    const int lane = tid & 63;
    const int l15  = lane & 15;
    const int lq   = lane >> 4;
    const long blockStart = (long)blockIdx.x * ET;
    const int is32 = flag[0];
    const int isf  = flag[1];

    // per-edge metadata
    if (tid < ET) {
        long e = blockStart + tid;
        int s = 0, o = 0; float ws = 0.f, wo = 0.f;
        if (e < N_EDGES) {
            s = get_pair(pairs, e, 0, is32);
            o = get_pair(pairs, e, 1, is32);
            float c = load_f(conf, e, isf);
            ws = __expf(c - mbuf[s]);
            wo = __expf(c - mbuf[o]);
        }
        sNode[tid] = s; sNode[ET + tid] = o;
        sW[tid] = ws;   sW[ET + tid] = wo;
    }
    __syncthreads();

    // gather concat feats: row e -> [objf[sub] (256) | objf[obj] (256)], bf16 in LDS
    if (isf) {
        const float4* objf4 = (const float4*)objf;  // 64 x float4 per node row
        #pragma unroll
        for (int it = 0; it < 32; ++it) {
            int idx = it * 256 + tid;        // [0, 8192)
            int row = idx >> 7;              // 0..63
            int g   = idx & 127;             // group of 4 cols
            float4 v = {0.f, 0.f, 0.f, 0.f};
            if (blockStart + row < N_EDGES) {
                int node = sNode[(g >> 6) * ET + row];
                v = objf4[(long)node * 64 + (g & 63)];
            }
            __hip_bfloat16 h0 = __float2bfloat16(v.x);
            __hip_bfloat16 h1 = __float2bfloat16(v.y);
            __hip_bfloat16 h2 = __float2bfloat16(v.z);
            __hip_bfloat16 h3 = __float2bfloat16(v.w);
            ushort2 p0 = { *(unsigned short*)&h0, *(unsigned short*)&h1 };
            ushort2 p1 = { *(unsigned short*)&h2, *(unsigned short*)&h3 };
            uint2 pk = { *(unsigned*)&p0, *(unsigned*)&p1 };
            *(uint2*)(sA + row * LDST + g * 4) = pk;
        }
    } else {
        const uint4* objf4 = (const uint4*)objf;  // 32 x 16B chunks per node row
        #pragma unroll
        for (int it = 0; it < 16; ++it) {
            int idx = it * 256 + tid;        // [0, 4096)
            int row = idx >> 6;
            int c   = idx & 63;
            uint4 v = {0u, 0u, 0u, 0u};
            if (blockStart + row < N_EDGES) {
                int node = sNode[(c >> 5) * ET + row];
                v = objf4[(long)node * 32 + (c & 31)];
            }
            *(uint4*)(sA + row * LDST + c * 8) = v;
        }
    }
    __syncthreads();

    const int nw = wave * 128;   // this wave's global n base (8 n-tiles of 16)
    f32x4 acc[4][8];
    #pragma unroll
    for (int mt = 0; mt < 4; ++mt)
        #pragma unroll
        for (int nt = 0; nt < 8; ++nt)
            acc[mt][nt] = (f32x4){0.f, 0.f, 0.f, 0.f};

    // ---- GEMM1: h = feats @ W1 ----
    {
        const bf16x8* bptr = (const bf16x8*)w1p;
        for (int tk = 0; tk < 16; ++tk) {
            bf16x8 a[4];
            #pragma unroll
            for (int mt = 0; mt < 4; ++mt)
                a[mt] = *(const bf16x8*)(sA + (mt * 16 + l15) * LDST + tk * 32 + lq * 8);
            #pragma unroll
            for (int nt = 0; nt < 8; ++nt) {
                bf16x8 b = bptr[(tk * 32 + wave * 8 + nt) * 64 + lane];
                #pragma unroll
                for (int mt = 0; mt < 4; ++mt)
                    acc[mt][nt] = __builtin_amdgcn_mfma_f32_16x16x32_bf16(a[mt], b, acc[mt][nt], 0, 0, 0);
            }
        }
    }
    __syncthreads();   // everyone done reading feats

    // bias + relu, write h (bf16) back into sA
    #pragma unroll
    for (int nt = 0; nt < 8; ++nt) {
        int n = nw + nt * 16 + l15;
        float bias = load_f(b1, n, isf);
        #pragma unroll
        for (int mt = 0; mt < 4; ++mt) {
            #pragma unroll
            for (int r = 0; r < 4; ++r) {
                int mrow = mt * 16 + lq * 4 + r;
                float v = acc[mt][nt][r] + bias;
                sA[mrow * LDST + n] = __float2bfloat16(fmaxf(v, 0.f));
            }
        }
    }
    __syncthreads();

    // ---- GEMM2: out = h @ W2 ----
    #pragma unroll
    for (int mt = 0; mt < 4; ++mt)
        #pragma unroll
        for (int nt = 0; nt < 8; ++nt)
            acc[mt][nt] = (f32x4){0.f, 0.f, 0.f, 0.f};
    {
        const bf16x8* bptr = (const bf16x8*)w2p;
        for (int tk = 0; tk < 16; ++tk) {
            bf16x8 a[4];
            #pragma unroll
            for (int mt = 0; mt < 4; ++mt)
                a[mt] = *(const bf16x8*)(sA + (mt * 16 + l15) * LDST + tk * 32 + lq * 8);
            #pragma unroll
            for (int nt = 0; nt < 8; ++nt) {
                bf16x8 b = bptr[(tk * 32 + wave * 8 + nt) * 64 + lane];
                #pragma unroll
                for (int mt = 0; mt < 4; ++mt)
                    acc[mt][nt] = __builtin_amdgcn_mfma_f32_16x16x32_bf16(a[mt], b, acc[mt][nt], 0, 0, 0);
            }
        }
    }

    // ---- epilogue: weighted packed-bf16 atomic scatter into numer ----
    // waves 0-1 hold out cols [0,256) -> sub endpoint; waves 2-3 cols [256,512) -> obj endpoint
    const int half  = wave >> 1;
    const int cbase = (wave & 1) * 128;
    float bias2[8];
    #pragma unroll
    for (int nt = 0; nt < 8; ++nt)
        bias2[nt] = load_f(b2, nw + nt * 16 + l15, isf);

    #pragma unroll
    for (int mt = 0; mt < 4; ++mt) {
        #pragma unroll
        for (int r = 0; r < 4; ++r) {
            int mrow = mt * 16 + lq * 4 + r;
            bool valid = (blockStart + mrow < N_EDGES);
            int   node = sNode[half * ET + mrow];
            float w    = sW[half * ET + mrow];
            __hip_bfloat16* nrow = numer + (long)node * DD + cbase;
            #pragma unroll
            for (int nt = 0; nt < 8; ++nt) {
                float v  = w * (acc[mt][nt][r] + bias2[nt]);
                float vp = __shfl_xor(v, 1, 64);   // partner col value
                if (valid && ((lane & 1) == 0)) {
                    // even lane: cols (nt*16 + l15, +1) — consecutive, 4B-aligned
                    atomic_pk_add_bf16(nrow + nt * 16 + l15, v, vp);
                }
            }
        }
    }
}

__global__ void finalize_k(const __hip_bfloat16* __restrict__ numer, const float* __restrict__ denom,
                           const float* __restrict__ mbuf, const void* __restrict__ objf,
                           void* __restrict__ out, const int* __restrict__ flag) {
    long i4 = (long)blockIdx.x * 256 + threadIdx.x;
    if (i4 >= (long)O_NODES * DD / 4) return;
    int isf = flag[1];
    long base = i4 * 4;
    int node = (int)(base >> 8);
    float sw  = __expf(10.0f - mbuf[node]);
    float inv = 1.0f / (denom[node] + sw);
    ushort4 nu = ((const ushort4*)numer)[i4];
    float n0 = __uint_as_float((unsigned)nu.x << 16);
    float n1 = __uint_as_float((unsigned)nu.y << 16);
    float n2 = __uint_as_float((unsigned)nu.z << 16);
    float n3 = __uint_as_float((unsigned)nu.w << 16);
    float o0, o1, o2, o3;
    if (isf) {
        float4 ov = ((const float4*)objf)[i4];
        o0 = ov.x; o1 = ov.y; o2 = ov.z; o3 = ov.w;
    } else {
        ushort4 ou = ((const ushort4*)objf)[i4];
        o0 = __uint_as_float((unsigned)ou.x << 16);
        o1 = __uint_as_float((unsigned)ou.y << 16);
        o2 = __uint_as_float((unsigned)ou.z << 16);
        o3 = __uint_as_float((unsigned)ou.w << 16);
    }
    float r0 = (n0 + sw * o0) * inv;
    float r1 = (n1 + sw * o1) * inv;
    float r2 = (n2 + sw * o2) * inv;
    float r3 = (n3 + sw * o3) * inv;
    if (isf) {
        float4 rv = { r0, r1, r2, r3 };
        ((float4*)out)[i4] = rv;
    } else {
        __hip_bfloat16 h0 = __float2bfloat16(r0);
        __hip_bfloat16 h1 = __float2bfloat16(r1);
        __hip_bfloat16 h2 = __float2bfloat16(r2);
        __hip_bfloat16 h3 = __float2bfloat16(r3);
        ushort4 ru;
        ru.x = *(unsigned short*)&h0;
        ru.y = *(unsigned short*)&h1;
        ru.z = *(unsigned short*)&h2;
        ru.w = *(unsigned short*)&h3;
        ((ushort4*)out)[i4] = ru;
    }
}

extern "C" void kernel_launch(void* const* d_in, const int* in_sizes, int n_in,
                              void* d_out, int out_size, void* d_ws, size_t ws_size,
                              hipStream_t stream) {
    const void* objf  = d_in[0];
    const int*  pairs = (const int*)d_in[1];
    const void* conf  = d_in[2];
    const void* W1    = d_in[3];
    const void* b1    = d_in[4];
    const void* W2    = d_in[5];
    const void* b2    = d_in[6];

    // workspace layout
    __hip_bfloat16* numer = (__hip_bfloat16*)d_ws;              // 25.6MB bf16
    float* denom = (float*)(numer + (size_t)O_NODES * DD);      // 50000 f32
    float* mbuf  = denom + O_NODES;                             // 50000 f32
    int*   flag  = (int*)(mbuf + O_NODES);                      // 2 ints (+pad)
    __hip_bfloat16* w1p = (__hip_bfloat16*)(flag + 4);          // 262144 bf16
    __hip_bfloat16* w2p = w1p + (size_t)KDIM * NDIM;            // 262144 bf16

    hipMemsetAsync(d_ws, 0, (size_t)O_NODES * DD * 2 + (size_t)O_NODES * 4, stream);
    init_misc<<<(O_NODES + 255) / 256, 256, 0, stream>>>(mbuf, flag);
    detect_fmt<<<32, 256, 0, stream>>>(pairs, flag);
    detect_dtype<<<1, 64, 0, stream>>>((const unsigned short*)objf, flag);
    edge_max<<<(N_EDGES + 255) / 256, 256, 0, stream>>>(pairs, conf, mbuf, flag);
    edge_denom<<<(N_EDGES + 255) / 256, 256, 0, stream>>>(pairs, conf, mbuf, denom, flag);
    repack_w<<<1024, 256, 0, stream>>>(W1, w1p, flag);
    repack_w<<<1024, 256, 0, stream>>>(W2, w2p, flag);

    size_t lds = (size_t)ET * LDST * 2 + 2 * ET * 4 + 2 * ET * 4;  // 67584 B
    fused_mlp<<<(N_EDGES + ET - 1) / ET, 256, lds, stream>>>(
        objf, pairs, conf, w1p, b1, w2p, b2, mbuf, numer, flag);

    finalize_k<<<(O_NODES * DD / 4 + 255) / 256, 256, 0, stream>>>(numer, denom, mbuf, objf, d_out, flag);
}

// Round 4
// 729.551 us; speedup vs baseline: 1.1024x; 1.1024x over previous
//
#include <hip/hip_runtime.h>
#include <hip/hip_bf16.h>

#define O_NODES 50000
#define N_EDGES 200000
#define DD 256
#define KDIM 512
#define NDIM 512
#define ET 128          // edges per block (R2 config: best measured)
#define LDST 520        // padded bf16 LDS row stride

typedef __bf16 bf16x8 __attribute__((ext_vector_type(8)));
typedef float  f32x4  __attribute__((ext_vector_type(4)));

__device__ __forceinline__ int get_pair(const int* __restrict__ p, long e, int which, int is32) {
    // is32: [sub0,obj0,...]; int64 case: [sub0,0,obj0,0,...] viewed as int32
    return is32 ? p[2 * e + which] : p[4 * e + 2 * which];
}

__device__ __forceinline__ float load_f(const void* p, long i, int is_f32) {
    if (is_f32) return ((const float*)p)[i];
    unsigned short u = ((const unsigned short*)p)[i];
    return __uint_as_float((unsigned)u << 16);
}

__device__ __forceinline__ float bf2f(unsigned short u) {
    return __uint_as_float((unsigned)u << 16);
}

// flag[0] = pairs-are-int32, flag[1] = floats-are-f32
__global__ void init_misc(float* mbuf, int* flag) {
    int i = blockIdx.x * 256 + threadIdx.x;
    if (i < O_NODES) mbuf[i] = 10.0f;
    if (i == 0) { flag[0] = 0; }
}

__global__ void detect_fmt(const int* __restrict__ pairs, int* flag) {
    int i = blockIdx.x * 256 + threadIdx.x;   // 8192 probes
    if (pairs[2 * i + 1] != 0) flag[0] = 1;
}

__global__ void detect_dtype(const unsigned short* __restrict__ w, int* flag) {
    // bf16 data: low half of each 32b word is a bf16 N(0,1) draw -> |v| in [0.004,16] w.p. ~99%
    // f32 data: low half is mantissa noise -> in range w.p. ~4%
    int lane = threadIdx.x & 63;
    unsigned short u = w[2 * lane];
    float v = fabsf(__uint_as_float((unsigned)u << 16));
    bool in_range = (v > 0.004f && v < 16.0f);
    unsigned long long m = __ballot(in_range);
    if (lane == 0) flag[1] = (__popcll(m) < 32) ? 1 : 0;
}

__global__ void edge_max(const int* __restrict__ pairs, const void* __restrict__ conf,
                         float* mbuf, const int* __restrict__ flag) {
    int i = blockIdx.x * 256 + threadIdx.x;
    if (i >= N_EDGES) return;
    int is32 = flag[0], isf = flag[1];
    int s = get_pair(pairs, i, 0, is32);
    int o = get_pair(pairs, i, 1, is32);
    float c = load_f(conf, i, isf);
    int cb = __float_as_int(c);
    // mbuf init = 10.0f (positive) -> signed-int atomicMax is order-correct
    atomicMax((int*)&mbuf[s], cb);
    atomicMax((int*)&mbuf[o], cb);
}

// denom + degree histogram (CSR mode); must run after edge_max
__global__ void edge_count_denom(const int* __restrict__ pairs, const void* __restrict__ conf,
                                 const float* __restrict__ mbuf, float* denom, int* count,
                                 const int* __restrict__ flag) {
    int i = blockIdx.x * 256 + threadIdx.x;
    if (i >= N_EDGES) return;
    int is32 = flag[0], isf = flag[1];
    int s = get_pair(pairs, i, 0, is32);
    int o = get_pair(pairs, i, 1, is32);
    float c = load_f(conf, i, isf);
    atomicAdd(&denom[s], __expf(c - mbuf[s]));
    atomicAdd(&denom[o], __expf(c - mbuf[o]));
    atomicAdd(&count[s], 1);
    atomicAdd(&count[o], 1);
}

// denom only (fallback mode)
__global__ void edge_denom(const int* __restrict__ pairs, const void* __restrict__ conf,
                           const float* __restrict__ mbuf, float* denom, const int* __restrict__ flag) {
    int i = blockIdx.x * 256 + threadIdx.x;
    if (i >= N_EDGES) return;
    int is32 = flag[0], isf = flag[1];
    int s = get_pair(pairs, i, 0, is32);
    int o = get_pair(pairs, i, 1, is32);
    float c = load_f(conf, i, isf);
    atomicAdd(&denom[s], __expf(c - mbuf[s]));
    atomicAdd(&denom[o], __expf(c - mbuf[o]));
}

// single-block exclusive scan of count[0..49999] -> offsets, cursor
#define SCAN_T 1024
#define SCAN_C 49
__global__ __launch_bounds__(SCAN_T) void scan50k(const int* __restrict__ count,
                                                  int* __restrict__ offsets,
                                                  int* __restrict__ cursor) {
    __shared__ int lsum[SCAN_T];
    int t = threadIdx.x;
    int base = t * SCAN_C;
    int end  = base + SCAN_C; if (end > O_NODES) end = O_NODES;
    int s = 0;
    for (int i = base; i < end; ++i) { offsets[i] = s; s += count[i]; }
    lsum[t] = s;
    __syncthreads();
    // Hillis-Steele inclusive scan over 1024
    for (int d = 1; d < SCAN_T; d <<= 1) {
        int v = (t >= d) ? lsum[t - d] : 0;
        __syncthreads();
        lsum[t] += v;
        __syncthreads();
    }
    int add = (t == 0) ? 0 : lsum[t - 1];
    for (int i = base; i < end; ++i) {
        int o = offsets[i] + add;
        offsets[i] = o;
        cursor[i]  = o;
    }
}

// incidence scatter: inc entry = edge*2 + half  (half 0 = sub part, 1 = obj part)
__global__ void scatter_inc(const int* __restrict__ pairs, int* __restrict__ cursor,
                            int* __restrict__ inc, const int* __restrict__ flag) {
    int i = blockIdx.x * 256 + threadIdx.x;
    if (i >= N_EDGES) return;
    int is32 = flag[0];
    int s = get_pair(pairs, i, 0, is32);
    int o = get_pair(pairs, i, 1, is32);
    int ps = atomicAdd(&cursor[s], 1);
    inc[ps] = 2 * i;
    int po = atomicAdd(&cursor[o], 1);
    inc[po] = 2 * i + 1;
}

// Pack W[k][n] (512x512 row-major) into MFMA-B-fragment order (bf16):
// bf16 flat idx ((tk*32+tn)*64 + lane)*8 + j holds B[tk*32 + (lane>>4)*8 + j][tn*16 + (lane&15)]
__global__ void repack_w(const void* __restrict__ W, __hip_bfloat16* __restrict__ Wp,
                         const int* __restrict__ flag) {
    int idx = blockIdx.x * 256 + threadIdx.x;  // < 262144
    int isf = flag[1];
    int j  = idx & 7;
    int l  = (idx >> 3) & 63;
    int tn = (idx >> 9) & 31;
    int tk = idx >> 14;
    int k = tk * 32 + (l >> 4) * 8 + j;
    int n = tn * 16 + (l & 15);
    Wp[idx] = __float2bfloat16(load_f(W, (long)k * NDIM + n, isf));
}

// CSR=1: stream weighted per-edge outputs to edgeout (no atomics)
// CSR=0: f32 atomicAdd into numer (fallback, R2-proven)
template<int CSR>
__global__ __launch_bounds__(512, 2) void fused_mlp(
    const void* __restrict__ objf,
    const int* __restrict__ pairs,
    const void* __restrict__ conf,
    const __hip_bfloat16* __restrict__ w1p,
    const void* __restrict__ b1,
    const __hip_bfloat16* __restrict__ w2p,
    const void* __restrict__ b2,
    const float* __restrict__ mbuf,
    float* __restrict__ numer,
    __hip_bfloat16* __restrict__ edgeout,
    const int* __restrict__ flag)
{
    extern __shared__ char smem[];
    __hip_bfloat16* sA    = (__hip_bfloat16*)smem;                 // ET x LDST bf16
    int*            sNode = (int*)(smem + ET * LDST * 2);          // [2][ET]
    float*          sW    = (float*)(smem + ET * LDST * 2 + 2 * ET * 4); // [2][ET]

    const int tid  = threadIdx.x;
    const int wave = tid >> 6;      // 0..7
    const int lane = tid & 63;
    const int l15  = lane & 15;
    const int lq   = lane >> 4;
    const long blockStart = (long)blockIdx.x * ET;
    const int is32 = flag[0];
    const int isf  = flag[1];

    // per-edge metadata
    if (tid < ET) {
        long e = blockStart + tid;
        int s = 0, o = 0; float ws = 0.f, wo = 0.f;
        if (e < N_EDGES) {
            s = get_pair(pairs, e, 0, is32);
            o = get_pair(pairs, e, 1, is32);
            float c = load_f(conf, e, isf);
            ws = __expf(c - mbuf[s]);
            wo = __expf(c - mbuf[o]);
        }
        sNode[tid] = s; sNode[ET + tid] = o;
        sW[tid] = ws;   sW[ET + tid] = wo;
    }
    __syncthreads();

    // gather concat feats: row e -> [objf[sub] (256) | objf[obj] (256)], bf16 in LDS
    if (isf) {
        const float4* objf4 = (const float4*)objf;  // 64 x float4 per node row
        #pragma unroll
        for (int it = 0; it < 32; ++it) {
            int idx = it * 512 + tid;        // [0, 16384)
            int row = idx >> 7;
            int g   = idx & 127;             // group of 4 cols
            float4 v = {0.f, 0.f, 0.f, 0.f};
            if (blockStart + row < N_EDGES) {
                int node = sNode[(g >> 6) * ET + row];
                v = objf4[(long)node * 64 + (g & 63)];
            }
            __hip_bfloat16 h0 = __float2bfloat16(v.x);
            __hip_bfloat16 h1 = __float2bfloat16(v.y);
            __hip_bfloat16 h2 = __float2bfloat16(v.z);
            __hip_bfloat16 h3 = __float2bfloat16(v.w);
            ushort2 p0 = { *(unsigned short*)&h0, *(unsigned short*)&h1 };
            ushort2 p1 = { *(unsigned short*)&h2, *(unsigned short*)&h3 };
            uint2 pk = { *(unsigned*)&p0, *(unsigned*)&p1 };
            *(uint2*)(sA + row * LDST + g * 4) = pk;
        }
    } else {
        const uint4* objf4 = (const uint4*)objf;  // 32 x 16B chunks per node row
        #pragma unroll
        for (int it = 0; it < 16; ++it) {
            int idx = it * 512 + tid;
            int row = idx >> 6;
            int c   = idx & 63;
            uint4 v = {0u, 0u, 0u, 0u};
            if (blockStart + row < N_EDGES) {
                int node = sNode[(c >> 5) * ET + row];
                v = objf4[(long)node * 32 + (c & 31)];
            }
            *(uint4*)(sA + row * LDST + c * 8) = v;
        }
    }
    __syncthreads();

    const int nw = wave * 64;   // this wave's global n base
    f32x4 acc[8][4];
    #pragma unroll
    for (int mt = 0; mt < 8; ++mt)
        #pragma unroll
        for (int nt = 0; nt < 4; ++nt)
            acc[mt][nt] = (f32x4){0.f, 0.f, 0.f, 0.f};

    // ---- GEMM1: h = feats @ W1 ----
    {
        const bf16x8* bptr = (const bf16x8*)w1p;
        for (int tk = 0; tk < 16; ++tk) {
            bf16x8 a[8];
            #pragma unroll
            for (int mt = 0; mt < 8; ++mt)
                a[mt] = *(const bf16x8*)(sA + (mt * 16 + l15) * LDST + tk * 32 + lq * 8);
            #pragma unroll
            for (int nt = 0; nt < 4; ++nt) {
                bf16x8 b = bptr[(tk * 32 + (nw >> 4) + nt) * 64 + lane];
                #pragma unroll
                for (int mt = 0; mt < 8; ++mt)
                    acc[mt][nt] = __builtin_amdgcn_mfma_f32_16x16x32_bf16(a[mt], b, acc[mt][nt], 0, 0, 0);
            }
        }
    }
    __syncthreads();   // everyone done reading feats

    // bias + relu, write h (bf16) back into sA
    #pragma unroll
    for (int nt = 0; nt < 4; ++nt) {
        int n = nw + nt * 16 + l15;
        float bias = load_f(b1, n, isf);
        #pragma unroll
        for (int mt = 0; mt < 8; ++mt) {
            #pragma unroll
            for (int r = 0; r < 4; ++r) {
                int mrow = mt * 16 + lq * 4 + r;
                float v = acc[mt][nt][r] + bias;
                sA[mrow * LDST + n] = __float2bfloat16(fmaxf(v, 0.f));
            }
        }
    }
    __syncthreads();

    // ---- GEMM2: out = h @ W2 ----
    #pragma unroll
    for (int mt = 0; mt < 8; ++mt)
        #pragma unroll
        for (int nt = 0; nt < 4; ++nt)
            acc[mt][nt] = (f32x4){0.f, 0.f, 0.f, 0.f};
    {
        const bf16x8* bptr = (const bf16x8*)w2p;
        for (int tk = 0; tk < 16; ++tk) {
            bf16x8 a[8];
            #pragma unroll
            for (int mt = 0; mt < 8; ++mt)
                a[mt] = *(const bf16x8*)(sA + (mt * 16 + l15) * LDST + tk * 32 + lq * 8);
            #pragma unroll
            for (int nt = 0; nt < 4; ++nt) {
                bf16x8 b = bptr[(tk * 32 + (nw >> 4) + nt) * 64 + lane];
                #pragma unroll
                for (int mt = 0; mt < 8; ++mt)
                    acc[mt][nt] = __builtin_amdgcn_mfma_f32_16x16x32_bf16(a[mt], b, acc[mt][nt], 0, 0, 0);
            }
        }
    }

    const int half = wave >> 2;   // cols [0,256) = sub endpoint, [256,512) = obj endpoint

    if constexpr (CSR) {
        // ---- epilogue: weighted bf16 rows -> sA -> coalesced stream to edgeout ----
        __syncthreads();   // GEMM2 LDS reads complete before overwrite
        float bias2[4];
        #pragma unroll
        for (int nt = 0; nt < 4; ++nt)
            bias2[nt] = load_f(b2, nw + nt * 16 + l15, isf);
        #pragma unroll
        for (int mt = 0; mt < 8; ++mt) {
            #pragma unroll
            for (int r = 0; r < 4; ++r) {
                int mrow = mt * 16 + lq * 4 + r;
                float w = sW[half * ET + mrow];
                #pragma unroll
                for (int nt = 0; nt < 4; ++nt) {
                    int n = nw + nt * 16 + l15;
                    sA[mrow * LDST + n] = __float2bfloat16(w * (acc[mt][nt][r] + bias2[nt]));
                }
            }
        }
        __syncthreads();
        // stream rows out: 512 bf16 per row = 64 uint4
        #pragma unroll
        for (int it = 0; it < 16; ++it) {
            int idx = it * 512 + tid;
            int row = idx >> 6;
            int ch  = idx & 63;
            if (blockStart + row < N_EDGES) {
                uint4 v = *(const uint4*)(sA + row * LDST + ch * 8);
                ((uint4*)edgeout)[(blockStart + row) * 64 + ch] = v;
            }
        }
    } else {
        // ---- fallback epilogue: weighted f32 atomic scatter into numer ----
        const int cbase = nw - half * 256;
        float bias2[4];
        #pragma unroll
        for (int nt = 0; nt < 4; ++nt)
            bias2[nt] = load_f(b2, nw + nt * 16 + l15, isf);

        #pragma unroll
        for (int mt = 0; mt < 8; ++mt) {
            #pragma unroll
            for (int r = 0; r < 4; ++r) {
                int mrow = mt * 16 + lq * 4 + r;
                if (blockStart + mrow < N_EDGES) {
                    int   node = sNode[half * ET + mrow];
                    float w    = sW[half * ET + mrow];
                    float* nrow = numer + (long)node * DD + cbase;
                    #pragma unroll
                    for (int nt = 0; nt < 4; ++nt) {
                        float v = acc[mt][nt][r] + bias2[nt];
                        atomicAdd(nrow + nt * 16 + l15, w * v);
                    }
                }
            }
        }
    }
}

// one wave per node: sum incidence rows (bf16, pre-weighted) in f32, add self term, divide
__global__ __launch_bounds__(256) void node_gather(
    const __hip_bfloat16* __restrict__ edgeout,
    const int* __restrict__ inc,
    const int* __restrict__ offsets,
    const int* __restrict__ count,
    const float* __restrict__ denom,
    const float* __restrict__ mbuf,
    const void* __restrict__ objf,
    void* __restrict__ out,
    const int* __restrict__ flag)
{
    int nid  = blockIdx.x * 4 + (threadIdx.x >> 6);
    if (nid >= O_NODES) return;
    int lane = threadIdx.x & 63;
    int isf  = flag[1];

    int off = offsets[nid];
    int deg = count[nid];

    float a0 = 0.f, a1 = 0.f, a2 = 0.f, a3 = 0.f;
    int j = (lane < deg) ? inc[off + lane] : 0;
    int m = deg < 64 ? deg : 64;
    const ushort4* ep = (const ushort4*)edgeout;   // 8B chunks; edge row = 128 chunks
    for (int i = 0; i < m; ++i) {
        int jj = __shfl(j, i, 64);
        ushort4 v = ep[(long)(jj >> 1) * 128 + (jj & 1) * 64 + lane];
        a0 += bf2f(v.x); a1 += bf2f(v.y); a2 += bf2f(v.z); a3 += bf2f(v.w);
    }
    for (int idx = off + 64; idx < off + deg; ++idx) {   // rare: deg > 64
        int jj = inc[idx];
        ushort4 v = ep[(long)(jj >> 1) * 128 + (jj & 1) * 64 + lane];
        a0 += bf2f(v.x); a1 += bf2f(v.y); a2 += bf2f(v.z); a3 += bf2f(v.w);
    }

    float sw  = __expf(10.0f - mbuf[nid]);
    float inv = 1.0f / (denom[nid] + sw);
    float o0, o1, o2, o3;
    if (isf) {
        float4 ov = ((const float4*)objf)[(long)nid * 64 + lane];
        o0 = ov.x; o1 = ov.y; o2 = ov.z; o3 = ov.w;
    } else {
        ushort4 ou = ((const ushort4*)objf)[(long)nid * 64 + lane];
        o0 = bf2f(ou.x); o1 = bf2f(ou.y); o2 = bf2f(ou.z); o3 = bf2f(ou.w);
    }
    float r0 = (a0 + sw * o0) * inv;
    float r1 = (a1 + sw * o1) * inv;
    float r2 = (a2 + sw * o2) * inv;
    float r3 = (a3 + sw * o3) * inv;
    if (isf) {
        float4 rv = { r0, r1, r2, r3 };
        ((float4*)out)[(long)nid * 64 + lane] = rv;
    } else {
        __hip_bfloat16 h0 = __float2bfloat16(r0);
        __hip_bfloat16 h1 = __float2bfloat16(r1);
        __hip_bfloat16 h2 = __float2bfloat16(r2);
        __hip_bfloat16 h3 = __float2bfloat16(r3);
        ushort4 ru;
        ru.x = *(unsigned short*)&h0;
        ru.y = *(unsigned short*)&h1;
        ru.z = *(unsigned short*)&h2;
        ru.w = *(unsigned short*)&h3;
        ((ushort4*)out)[(long)nid * 64 + lane] = ru;
    }
}

// fallback finalize (f32 numer)
__global__ void finalize_k(const float* __restrict__ numer, const float* __restrict__ denom,
                           const float* __restrict__ mbuf, const void* __restrict__ objf,
                           void* __restrict__ out, const int* __restrict__ flag) {
    long i4 = (long)blockIdx.x * 256 + threadIdx.x;
    if (i4 >= (long)O_NODES * DD / 4) return;
    int isf = flag[1];
    long base = i4 * 4;
    int node = (int)(base >> 8);
    float sw  = __expf(10.0f - mbuf[node]);
    float inv = 1.0f / (denom[node] + sw);
    f32x4 nm = *(const f32x4*)(numer + base);
    float o0, o1, o2, o3;
    if (isf) {
        float4 ov = ((const float4*)objf)[i4];
        o0 = ov.x; o1 = ov.y; o2 = ov.z; o3 = ov.w;
    } else {
        ushort4 ou = ((const ushort4*)objf)[i4];
        o0 = bf2f(ou.x); o1 = bf2f(ou.y); o2 = bf2f(ou.z); o3 = bf2f(ou.w);
    }
    float r0 = (nm[0] + sw * o0) * inv;
    float r1 = (nm[1] + sw * o1) * inv;
    float r2 = (nm[2] + sw * o2) * inv;
    float r3 = (nm[3] + sw * o3) * inv;
    if (isf) {
        float4 rv = { r0, r1, r2, r3 };
        ((float4*)out)[i4] = rv;
    } else {
        __hip_bfloat16 h0 = __float2bfloat16(r0);
        __hip_bfloat16 h1 = __float2bfloat16(r1);
        __hip_bfloat16 h2 = __float2bfloat16(r2);
        __hip_bfloat16 h3 = __float2bfloat16(r3);
        ushort4 ru;
        ru.x = *(unsigned short*)&h0;
        ru.y = *(unsigned short*)&h1;
        ru.z = *(unsigned short*)&h2;
        ru.w = *(unsigned short*)&h3;
        ((ushort4*)out)[i4] = ru;
    }
}

extern "C" void kernel_launch(void* const* d_in, const int* in_sizes, int n_in,
                              void* d_out, int out_size, void* d_ws, size_t ws_size,
                              hipStream_t stream) {
    const void* objf  = d_in[0];
    const int*  pairs = (const int*)d_in[1];
    const void* conf  = d_in[2];
    const void* W1    = d_in[3];
    const void* b1    = d_in[4];
    const void* W2    = d_in[5];
    const void* b2    = d_in[6];

    const size_t EOUT = (size_t)N_EDGES * 512 * 2;          // 204,800,000 B
    const size_t need_csr = EOUT + 6 * 200000 + 1600000 + 64 + 2 * 524288;
    char* ws = (char*)d_ws;

    if (ws_size >= need_csr) {
        // ---- CSR layout ----
        __hip_bfloat16* edgeout = (__hip_bfloat16*)ws;
        float* denom   = (float*)(ws + EOUT);
        int*   count   = (int*)  (ws + EOUT + 200000);
        float* mbuf    = (float*)(ws + EOUT + 400000);
        int*   offsets = (int*)  (ws + EOUT + 600000);
        int*   cursor  = (int*)  (ws + EOUT + 800000);
        int*   inc     = (int*)  (ws + EOUT + 1000000);
        int*   flag    = (int*)  (ws + EOUT + 2600000);
        __hip_bfloat16* w1p = (__hip_bfloat16*)(ws + EOUT + 2600064);
        __hip_bfloat16* w2p = w1p + (size_t)KDIM * NDIM;

        hipMemsetAsync(denom, 0, 400000, stream);   // denom + count
        init_misc<<<(O_NODES + 255) / 256, 256, 0, stream>>>(mbuf, flag);
        detect_fmt<<<32, 256, 0, stream>>>(pairs, flag);
        detect_dtype<<<1, 64, 0, stream>>>((const unsigned short*)objf, flag);
        edge_max<<<(N_EDGES + 255) / 256, 256, 0, stream>>>(pairs, conf, mbuf, flag);
        edge_count_denom<<<(N_EDGES + 255) / 256, 256, 0, stream>>>(pairs, conf, mbuf, denom, count, flag);
        scan50k<<<1, SCAN_T, 0, stream>>>(count, offsets, cursor);
        scatter_inc<<<(N_EDGES + 255) / 256, 256, 0, stream>>>(pairs, cursor, inc, flag);
        repack_w<<<1024, 256, 0, stream>>>(W1, w1p, flag);
        repack_w<<<1024, 256, 0, stream>>>(W2, w2p, flag);

        size_t lds = (size_t)ET * LDST * 2 + 2 * ET * 4 + 2 * ET * 4;  // 135168 B
        fused_mlp<1><<<(N_EDGES + ET - 1) / ET, 512, lds, stream>>>(
            objf, pairs, conf, w1p, b1, w2p, b2, mbuf, (float*)nullptr, edgeout, flag);

        node_gather<<<(O_NODES + 3) / 4, 256, 0, stream>>>(
            edgeout, inc, offsets, count, denom, mbuf, objf, d_out, flag);
    } else {
        // ---- fallback: R2-proven atomic path ----
        float* numer = (float*)ws;                              // 12.8M f32
        float* denom = numer + (size_t)O_NODES * DD;
        float* mbuf  = denom + O_NODES;
        int*   flag  = (int*)(mbuf + O_NODES);
        __hip_bfloat16* w1p = (__hip_bfloat16*)(flag + 4);
        __hip_bfloat16* w2p = w1p + (size_t)KDIM * NDIM;

        hipMemsetAsync(numer, 0, (size_t)(O_NODES * DD + O_NODES) * sizeof(float), stream);
        init_misc<<<(O_NODES + 255) / 256, 256, 0, stream>>>(mbuf, flag);
        detect_fmt<<<32, 256, 0, stream>>>(pairs, flag);
        detect_dtype<<<1, 64, 0, stream>>>((const unsigned short*)objf, flag);
        edge_max<<<(N_EDGES + 255) / 256, 256, 0, stream>>>(pairs, conf, mbuf, flag);
        edge_denom<<<(N_EDGES + 255) / 256, 256, 0, stream>>>(pairs, conf, mbuf, denom, flag);
        repack_w<<<1024, 256, 0, stream>>>(W1, w1p, flag);
        repack_w<<<1024, 256, 0, stream>>>(W2, w2p, flag);

        size_t lds = (size_t)ET * LDST * 2 + 2 * ET * 4 + 2 * ET * 4;  // 135168 B
        fused_mlp<0><<<(N_EDGES + ET - 1) / ET, 512, lds, stream>>>(
            objf, pairs, conf, w1p, b1, w2p, b2, mbuf, numer, (__hip_bfloat16*)nullptr, flag);

        finalize_k<<<(O_NODES * DD / 4 + 255) / 256, 256, 0, stream>>>(numer, denom, mbuf, objf, d_out, flag);
    }
}

// Round 5
// 627.303 us; speedup vs baseline: 1.2820x; 1.1630x over previous
//
#include <hip/hip_runtime.h>
#include <hip/hip_bf16.h>
#include <hip/hip_fp8.h>

#define O_NODES 50000
#define N_EDGES 200000
#define DD 256
#define KDIM 512
#define NDIM 512
#define ET 64           // edges per block; 200000 % 64 == 0 -> all tiles full
#define LDSF8 528       // padded fp8 LDS row stride (512 + 16; 16B-aligned rows)

typedef float f32x4 __attribute__((ext_vector_type(4)));

// ---------- fp8 e4m3 helpers ----------
__device__ __forceinline__ unsigned pack4_fp8(float a, float b, float c, float d) {
#if __has_builtin(__builtin_amdgcn_cvt_pk_fp8_f32)
    int v = __builtin_amdgcn_cvt_pk_fp8_f32(a, b, 0, false);
    v = __builtin_amdgcn_cvt_pk_fp8_f32(c, d, v, true);
    return (unsigned)v;
#else
    __hip_fp8_e4m3 x(a), y(b), z(c), w(d);
    return (unsigned)x.__x | ((unsigned)y.__x << 8) | ((unsigned)z.__x << 16) | ((unsigned)w.__x << 24);
#endif
}

__device__ __forceinline__ unsigned char f2fp8(float x) {
#if __has_builtin(__builtin_amdgcn_cvt_pk_fp8_f32)
    return (unsigned char)(__builtin_amdgcn_cvt_pk_fp8_f32(x, x, 0, false) & 0xff);
#else
    __hip_fp8_e4m3 t(x); return t.__x;
#endif
}

__device__ __forceinline__ f32x4 unpack4_fp8(unsigned v) {
#if __has_builtin(__builtin_amdgcn_cvt_pk_f32_fp8)
    auto lo = __builtin_amdgcn_cvt_pk_f32_fp8((int)v, false);
    auto hi = __builtin_amdgcn_cvt_pk_f32_fp8((int)v, true);
    return (f32x4){lo[0], lo[1], hi[0], hi[1]};
#else
    __hip_fp8_e4m3 t0, t1, t2, t3;
    t0.__x = v & 0xff; t1.__x = (v >> 8) & 0xff; t2.__x = (v >> 16) & 0xff; t3.__x = (v >> 24) & 0xff;
    return (f32x4){(float)t0, (float)t1, (float)t2, (float)t3};
#endif
}

__device__ __forceinline__ f32x4 mfma_fp8(long a, long b, f32x4 c) {
    return __builtin_amdgcn_mfma_f32_16x16x32_fp8_fp8(a, b, c, 0, 0, 0);
}

// ---------- generic input helpers ----------
__device__ __forceinline__ int get_pair(const int* __restrict__ p, long e, int which, int is32) {
    // is32: [sub0,obj0,...]; int64 case: [sub0,0,obj0,0,...] viewed as int32
    return is32 ? p[2 * e + which] : p[4 * e + 2 * which];
}

__device__ __forceinline__ float load_f(const void* p, long i, int is_f32) {
    if (is_f32) return ((const float*)p)[i];
    unsigned short u = ((const unsigned short*)p)[i];
    return __uint_as_float((unsigned)u << 16);
}

__device__ __forceinline__ float bf2f(unsigned short u) {
    return __uint_as_float((unsigned)u << 16);
}

// flag[0] = pairs-are-int32, flag[1] = floats-are-f32
__global__ void init_misc(float* mbuf, int* flag) {
    int i = blockIdx.x * 256 + threadIdx.x;
    if (i < O_NODES) mbuf[i] = 10.0f;
    if (i == 0) { flag[0] = 0; }
}

__global__ void detect_fmt(const int* __restrict__ pairs, int* flag) {
    int i = blockIdx.x * 256 + threadIdx.x;   // 8192 probes
    if (pairs[2 * i + 1] != 0) flag[0] = 1;
}

__global__ void detect_dtype(const unsigned short* __restrict__ w, int* flag) {
    // bf16 data: low half of each 32b word is a bf16 N(0,1) draw -> |v| in [0.004,16] w.p. ~99%
    // f32 data: low half is mantissa noise -> in range w.p. ~4%
    int lane = threadIdx.x & 63;
    unsigned short u = w[2 * lane];
    float v = fabsf(__uint_as_float((unsigned)u << 16));
    bool in_range = (v > 0.004f && v < 16.0f);
    unsigned long long m = __ballot(in_range);
    if (lane == 0) flag[1] = (__popcll(m) < 32) ? 1 : 0;
}

// max + degree histogram in one pass (count doesn't depend on max)
__global__ void edge_max_count(const int* __restrict__ pairs, const void* __restrict__ conf,
                               float* mbuf, int* count, const int* __restrict__ flag) {
    int i = blockIdx.x * 256 + threadIdx.x;
    if (i >= N_EDGES) return;
    int is32 = flag[0], isf = flag[1];
    int s = get_pair(pairs, i, 0, is32);
    int o = get_pair(pairs, i, 1, is32);
    float c = load_f(conf, i, isf);
    int cb = __float_as_int(c);
    // mbuf init = 10.0f (positive) -> signed-int atomicMax is order-correct
    atomicMax((int*)&mbuf[s], cb);
    atomicMax((int*)&mbuf[o], cb);
    atomicAdd(&count[s], 1);
    atomicAdd(&count[o], 1);
}

__global__ void edge_denom(const int* __restrict__ pairs, const void* __restrict__ conf,
                           const float* __restrict__ mbuf, float* denom, const int* __restrict__ flag) {
    int i = blockIdx.x * 256 + threadIdx.x;
    if (i >= N_EDGES) return;
    int is32 = flag[0], isf = flag[1];
    int s = get_pair(pairs, i, 0, is32);
    int o = get_pair(pairs, i, 1, is32);
    float c = load_f(conf, i, isf);
    atomicAdd(&denom[s], __expf(c - mbuf[s]));
    atomicAdd(&denom[o], __expf(c - mbuf[o]));
}

// coalesced single-block scan: tiles of 1024, wave shfl-scan + cross-wave combine
#define SCAN_T 1024
__global__ __launch_bounds__(SCAN_T) void scan50k(const int* __restrict__ count,
                                                  int* __restrict__ offsets,
                                                  int* __restrict__ cursor) {
    __shared__ int wsum[16];
    __shared__ int carry_s;
    int t = threadIdx.x;
    int lane = t & 63, wid = t >> 6;
    if (t == 0) carry_s = 0;
    __syncthreads();
    for (int base = 0; base < O_NODES; base += SCAN_T) {
        int i = base + t;
        int c = (i < O_NODES) ? count[i] : 0;
        int v = c;
        #pragma unroll
        for (int d = 1; d < 64; d <<= 1) {
            int u = __shfl_up(v, d, 64);
            if (lane >= d) v += u;
        }
        if (lane == 63) wsum[wid] = v;
        __syncthreads();
        if (wid == 0) {
            int s = (lane < 16) ? wsum[lane] : 0;
            #pragma unroll
            for (int d = 1; d < 16; d <<= 1) {
                int u = __shfl_up(s, d, 64);
                if (lane >= d) s += u;
            }
            if (lane < 16) wsum[lane] = s;
        }
        __syncthreads();
        int wprefix = (wid == 0) ? 0 : wsum[wid - 1];
        int excl = carry_s + wprefix + v - c;
        if (i < O_NODES) { offsets[i] = excl; cursor[i] = excl; }
        int total = wsum[15];
        __syncthreads();
        if (t == 0) carry_s += total;
        __syncthreads();
    }
}

// incidence scatter: inc entry = edge*2 + half  (half 0 = sub part, 1 = obj part)
__global__ void scatter_inc(const int* __restrict__ pairs, int* __restrict__ cursor,
                            int* __restrict__ inc, const int* __restrict__ flag) {
    int i = blockIdx.x * 256 + threadIdx.x;
    if (i >= N_EDGES) return;
    int is32 = flag[0];
    int s = get_pair(pairs, i, 0, is32);
    int o = get_pair(pairs, i, 1, is32);
    int ps = atomicAdd(&cursor[s], 1);
    inc[ps] = 2 * i;
    int po = atomicAdd(&cursor[o], 1);
    inc[po] = 2 * i + 1;
}

// Pack both W (512x512 row-major) into fp8 MFMA-B-fragment order:
// byte idx ((tk*32+tn)*64 + lane)*8 + j holds B[tk*32 + (lane>>4)*8 + j][tn*16 + (lane&15)]
__global__ void repack_w2(const void* __restrict__ W1, const void* __restrict__ W2,
                          unsigned char* __restrict__ Wp1, unsigned char* __restrict__ Wp2,
                          const int* __restrict__ flag) {
    int b = blockIdx.x;
    const void* W = (b < 1024) ? W1 : W2;
    unsigned char* Wp = (b < 1024) ? Wp1 : Wp2;
    int idx = ((b & 1023) << 8) + threadIdx.x;   // < 262144
    int isf = flag[1];
    int j  = idx & 7;
    int l  = (idx >> 3) & 63;
    int tn = (idx >> 9) & 31;
    int tk = idx >> 14;
    int k = tk * 32 + (l >> 4) * 8 + j;
    int n = tn * 16 + (l & 15);
    Wp[idx] = f2fp8(load_f(W, (long)k * NDIM + n, isf));
}

// CSR=1: stream UNWEIGHTED per-edge outputs (fp8) to edgeout
// CSR=0: weighted f32 atomicAdd into numer (fallback)
template<int CSR>
__global__ __launch_bounds__(512, 4) void fused_mlp(
    const void* __restrict__ objf,
    const int* __restrict__ pairs,
    const void* __restrict__ conf,
    const unsigned char* __restrict__ w1p,
    const void* __restrict__ b1,
    const unsigned char* __restrict__ w2p,
    const void* __restrict__ b2,
    const float* __restrict__ mbuf,
    float* __restrict__ numer,
    unsigned char* __restrict__ edgeout,
    const int* __restrict__ flag)
{
    extern __shared__ char smem[];
    unsigned char* sA    = (unsigned char*)smem;           // ET x LDSF8 fp8
    int*           sNode = (int*)(smem + ET * LDSF8);      // [2][ET]
    float*         sW    = (float*)(smem + ET * LDSF8 + 2 * ET * 4); // [2][ET]

    const int tid  = threadIdx.x;
    const int wave = tid >> 6;      // 0..7
    const int lane = tid & 63;
    const int l15  = lane & 15;
    const int lq   = lane >> 4;
    const long blockStart = (long)blockIdx.x * ET;
    const int is32 = flag[0];
    const int isf  = flag[1];

    // per-edge metadata (all tiles full: 200000 % 64 == 0)
    if (tid < ET) {
        long e = blockStart + tid;
        int s = get_pair(pairs, e, 0, is32);
        int o = get_pair(pairs, e, 1, is32);
        float c = load_f(conf, e, isf);
        sNode[tid]      = s; sNode[ET + tid] = o;
        sW[tid]         = __expf(c - mbuf[s]);
        sW[ET + tid]    = __expf(c - mbuf[o]);
    }
    __syncthreads();

    // gather concat feats -> fp8 LDS: row e = [objf[sub] (256) | objf[obj] (256)]
    // 64 rows x 128 uint-groups (4 cols each) = 8192; 16 per thread
    #pragma unroll
    for (int it = 0; it < 16; ++it) {
        int idx = it * 512 + tid;
        int row = idx >> 7;
        int g   = idx & 127;
        int node = sNode[(g >> 6) * ET + row];
        float x0, x1, x2, x3;
        if (isf) {
            float4 v = ((const float4*)objf)[(long)node * 64 + (g & 63)];
            x0 = v.x; x1 = v.y; x2 = v.z; x3 = v.w;
        } else {
            ushort4 u = ((const ushort4*)objf)[(long)node * 64 + (g & 63)];
            x0 = bf2f(u.x); x1 = bf2f(u.y); x2 = bf2f(u.z); x3 = bf2f(u.w);
        }
        *(unsigned*)(sA + row * LDSF8 + g * 4) = pack4_fp8(x0, x1, x2, x3);
    }
    __syncthreads();

    const int nw = wave * 64;   // wave's n base; tn = wave*4 + nt
    f32x4 acc[4][4];
    #pragma unroll
    for (int mt = 0; mt < 4; ++mt)
        #pragma unroll
        for (int nt = 0; nt < 4; ++nt)
            acc[mt][nt] = (f32x4){0.f, 0.f, 0.f, 0.f};

    // ---- GEMM1: h = feats @ W1 (fp8) ----
    {
        const long* bq = (const long*)w1p;
        for (int tk = 0; tk < 16; ++tk) {
            long a[4];
            #pragma unroll
            for (int mt = 0; mt < 4; ++mt)
                a[mt] = *(const long*)(sA + (mt * 16 + l15) * LDSF8 + tk * 32 + lq * 8);
            #pragma unroll
            for (int nt = 0; nt < 4; ++nt) {
                long b = bq[(tk * 32 + wave * 4 + nt) * 64 + lane];
                #pragma unroll
                for (int mt = 0; mt < 4; ++mt)
                    acc[mt][nt] = mfma_fp8(a[mt], b, acc[mt][nt]);
            }
        }
    }
    __syncthreads();

    // bias + relu, h (fp8) back into sA
    #pragma unroll
    for (int nt = 0; nt < 4; ++nt) {
        int n = nw + nt * 16 + l15;
        float bias = load_f(b1, n, isf);
        #pragma unroll
        for (int mt = 0; mt < 4; ++mt) {
            #pragma unroll
            for (int r = 0; r < 4; ++r) {
                int mrow = mt * 16 + lq * 4 + r;
                sA[mrow * LDSF8 + n] = f2fp8(fmaxf(acc[mt][nt][r] + bias, 0.f));
            }
        }
    }
    __syncthreads();

    // ---- GEMM2: out = h @ W2 (fp8) ----
    #pragma unroll
    for (int mt = 0; mt < 4; ++mt)
        #pragma unroll
        for (int nt = 0; nt < 4; ++nt)
            acc[mt][nt] = (f32x4){0.f, 0.f, 0.f, 0.f};
    {
        const long* bq = (const long*)w2p;
        for (int tk = 0; tk < 16; ++tk) {
            long a[4];
            #pragma unroll
            for (int mt = 0; mt < 4; ++mt)
                a[mt] = *(const long*)(sA + (mt * 16 + l15) * LDSF8 + tk * 32 + lq * 8);
            #pragma unroll
            for (int nt = 0; nt < 4; ++nt) {
                long b = bq[(tk * 32 + wave * 4 + nt) * 64 + lane];
                #pragma unroll
                for (int mt = 0; mt < 4; ++mt)
                    acc[mt][nt] = mfma_fp8(a[mt], b, acc[mt][nt]);
            }
        }
    }

    if constexpr (CSR) {
        // unweighted out (fp8) -> sA -> coalesced stream
        __syncthreads();
        float bias2[4];
        #pragma unroll
        for (int nt = 0; nt < 4; ++nt)
            bias2[nt] = load_f(b2, nw + nt * 16 + l15, isf);
        #pragma unroll
        for (int nt = 0; nt < 4; ++nt) {
            int n = nw + nt * 16 + l15;
            #pragma unroll
            for (int mt = 0; mt < 4; ++mt) {
                #pragma unroll
                for (int r = 0; r < 4; ++r) {
                    int mrow = mt * 16 + lq * 4 + r;
                    sA[mrow * LDSF8 + n] = f2fp8(acc[mt][nt][r] + bias2[nt]);
                }
            }
        }
        __syncthreads();
        // stream: 64 rows x 32 uint4 = 2048; 4 per thread
        #pragma unroll
        for (int it = 0; it < 4; ++it) {
            int idx = it * 512 + tid;
            int row = idx >> 5;
            int ch  = idx & 31;
            uint4 v = *(const uint4*)(sA + row * LDSF8 + ch * 16);
            ((uint4*)edgeout)[(blockStart + row) * 32 + ch] = v;
        }
    } else {
        // fallback: weighted f32 atomic scatter
        const int half  = wave >> 2;
        const int cbase = nw - half * 256;
        float bias2[4];
        #pragma unroll
        for (int nt = 0; nt < 4; ++nt)
            bias2[nt] = load_f(b2, nw + nt * 16 + l15, isf);
        #pragma unroll
        for (int mt = 0; mt < 4; ++mt) {
            #pragma unroll
            for (int r = 0; r < 4; ++r) {
                int mrow = mt * 16 + lq * 4 + r;
                int   node = sNode[half * ET + mrow];
                float w    = sW[half * ET + mrow];
                float* nrow = numer + (long)node * DD + cbase;
                #pragma unroll
                for (int nt = 0; nt < 4; ++nt)
                    atomicAdd(nrow + nt * 16 + l15, w * (acc[mt][nt][r] + bias2[nt]));
            }
        }
    }
}

// one wave per node: weighted sum of fp8 incidence half-rows (unroll 4), self term, divide
__global__ __launch_bounds__(256) void node_gather(
    const unsigned* __restrict__ edgeout,   // uint view; edge row = 128 uints
    const int* __restrict__ inc,
    const int* __restrict__ offsets,
    const int* __restrict__ count,
    const float* __restrict__ denom,
    const float* __restrict__ mbuf,
    const void* __restrict__ conf,
    const void* __restrict__ objf,
    void* __restrict__ out,
    const int* __restrict__ flag)
{
    int nid  = blockIdx.x * 4 + (threadIdx.x >> 6);
    if (nid >= O_NODES) return;
    int lane = threadIdx.x & 63;
    int isf  = flag[1];

    int off = offsets[nid];
    int deg = count[nid];
    float mnode = mbuf[nid];

    // per-lane precompute of incidence id + weight
    int j = 0; float wg = 0.f;
    if (lane < deg) {
        j  = inc[off + lane];
        wg = __expf(load_f(conf, j >> 1, isf) - mnode);
    }

    float a0 = 0.f, a1 = 0.f, a2 = 0.f, a3 = 0.f;
    int m  = deg < 64 ? deg : 64;
    int m4 = m & ~3;
    int i = 0;
    for (; i < m4; i += 4) {
        int   j0 = __shfl(j, i, 64),   j1 = __shfl(j, i + 1, 64);
        int   j2 = __shfl(j, i + 2, 64), j3 = __shfl(j, i + 3, 64);
        float w0 = __shfl(wg, i, 64),  w1 = __shfl(wg, i + 1, 64);
        float w2 = __shfl(wg, i + 2, 64), w3 = __shfl(wg, i + 3, 64);
        unsigned v0 = edgeout[(long)(j0 >> 1) * 128 + (j0 & 1) * 64 + lane];
        unsigned v1 = edgeout[(long)(j1 >> 1) * 128 + (j1 & 1) * 64 + lane];
        unsigned v2 = edgeout[(long)(j2 >> 1) * 128 + (j2 & 1) * 64 + lane];
        unsigned v3 = edgeout[(long)(j3 >> 1) * 128 + (j3 & 1) * 64 + lane];
        f32x4 f0 = unpack4_fp8(v0), f1 = unpack4_fp8(v1), f2 = unpack4_fp8(v2), f3 = unpack4_fp8(v3);
        a0 += w0 * f0[0] + w1 * f1[0] + w2 * f2[0] + w3 * f3[0];
        a1 += w0 * f0[1] + w1 * f1[1] + w2 * f2[1] + w3 * f3[1];
        a2 += w0 * f0[2] + w1 * f1[2] + w2 * f2[2] + w3 * f3[2];
        a3 += w0 * f0[3] + w1 * f1[3] + w2 * f2[3] + w3 * f3[3];
    }
    for (; i < m; ++i) {
        int   jj = __shfl(j, i, 64);
        float ww = __shfl(wg, i, 64);
        unsigned v = edgeout[(long)(jj >> 1) * 128 + (jj & 1) * 64 + lane];
        f32x4 f = unpack4_fp8(v);
        a0 += ww * f[0]; a1 += ww * f[1]; a2 += ww * f[2]; a3 += ww * f[3];
    }
    for (int idx = off + 64; idx < off + deg; ++idx) {   // rare deg > 64
        int jj = inc[idx];
        float ww = __expf(load_f(conf, jj >> 1, isf) - mnode);
        unsigned v = edgeout[(long)(jj >> 1) * 128 + (jj & 1) * 64 + lane];
        f32x4 f = unpack4_fp8(v);
        a0 += ww * f[0]; a1 += ww * f[1]; a2 += ww * f[2]; a3 += ww * f[3];
    }

    float sw  = __expf(10.0f - mnode);
    float inv = 1.0f / (denom[nid] + sw);
    float o0, o1, o2, o3;
    if (isf) {
        float4 ov = ((const float4*)objf)[(long)nid * 64 + lane];
        o0 = ov.x; o1 = ov.y; o2 = ov.z; o3 = ov.w;
    } else {
        ushort4 ou = ((const ushort4*)objf)[(long)nid * 64 + lane];
        o0 = bf2f(ou.x); o1 = bf2f(ou.y); o2 = bf2f(ou.z); o3 = bf2f(ou.w);
    }
    float r0 = (a0 + sw * o0) * inv;
    float r1 = (a1 + sw * o1) * inv;
    float r2 = (a2 + sw * o2) * inv;
    float r3 = (a3 + sw * o3) * inv;
    if (isf) {
        float4 rv = { r0, r1, r2, r3 };
        ((float4*)out)[(long)nid * 64 + lane] = rv;
    } else {
        __hip_bfloat16 h0 = __float2bfloat16(r0);
        __hip_bfloat16 h1 = __float2bfloat16(r1);
        __hip_bfloat16 h2 = __float2bfloat16(r2);
        __hip_bfloat16 h3 = __float2bfloat16(r3);
        ushort4 ru;
        ru.x = *(unsigned short*)&h0;
        ru.y = *(unsigned short*)&h1;
        ru.z = *(unsigned short*)&h2;
        ru.w = *(unsigned short*)&h3;
        ((ushort4*)out)[(long)nid * 64 + lane] = ru;
    }
}

// fallback finalize (f32 numer)
__global__ void finalize_k(const float* __restrict__ numer, const float* __restrict__ denom,
                           const float* __restrict__ mbuf, const void* __restrict__ objf,
                           void* __restrict__ out, const int* __restrict__ flag) {
    long i4 = (long)blockIdx.x * 256 + threadIdx.x;
    if (i4 >= (long)O_NODES * DD / 4) return;
    int isf = flag[1];
    long base = i4 * 4;
    int node = (int)(base >> 8);
    float sw  = __expf(10.0f - mbuf[node]);
    float inv = 1.0f / (denom[node] + sw);
    f32x4 nm = *(const f32x4*)(numer + base);
    float o0, o1, o2, o3;
    if (isf) {
        float4 ov = ((const float4*)objf)[i4];
        o0 = ov.x; o1 = ov.y; o2 = ov.z; o3 = ov.w;
    } else {
        ushort4 ou = ((const ushort4*)objf)[i4];
        o0 = bf2f(ou.x); o1 = bf2f(ou.y); o2 = bf2f(ou.z); o3 = bf2f(ou.w);
    }
    float r0 = (nm[0] + sw * o0) * inv;
    float r1 = (nm[1] + sw * o1) * inv;
    float r2 = (nm[2] + sw * o2) * inv;
    float r3 = (nm[3] + sw * o3) * inv;
    if (isf) {
        float4 rv = { r0, r1, r2, r3 };
        ((float4*)out)[i4] = rv;
    } else {
        __hip_bfloat16 h0 = __float2bfloat16(r0);
        __hip_bfloat16 h1 = __float2bfloat16(r1);
        __hip_bfloat16 h2 = __float2bfloat16(r2);
        __hip_bfloat16 h3 = __float2bfloat16(r3);
        ushort4 ru;
        ru.x = *(unsigned short*)&h0;
        ru.y = *(unsigned short*)&h1;
        ru.z = *(unsigned short*)&h2;
        ru.w = *(unsigned short*)&h3;
        ((ushort4*)out)[i4] = ru;
    }
}

extern "C" void kernel_launch(void* const* d_in, const int* in_sizes, int n_in,
                              void* d_out, int out_size, void* d_ws, size_t ws_size,
                              hipStream_t stream) {
    const void* objf  = d_in[0];
    const int*  pairs = (const int*)d_in[1];
    const void* conf  = d_in[2];
    const void* W1    = d_in[3];
    const void* b1    = d_in[4];
    const void* W2    = d_in[5];
    const void* b2    = d_in[6];

    const size_t EOUT = (size_t)N_EDGES * 512;              // 102,400,000 B (fp8)
    const size_t need_csr = EOUT + 2600064 + 2 * 262144;
    char* ws = (char*)d_ws;
    size_t lds = (size_t)ET * LDSF8 + 4 * ET * 4;           // 34816 B

    if (ws_size >= need_csr) {
        unsigned char* edgeout = (unsigned char*)ws;
        float* denom   = (float*)(ws + EOUT);
        int*   count   = (int*)  (ws + EOUT + 200000);
        float* mbuf    = (float*)(ws + EOUT + 400000);
        int*   offsets = (int*)  (ws + EOUT + 600000);
        int*   cursor  = (int*)  (ws + EOUT + 800000);
        int*   inc     = (int*)  (ws + EOUT + 1000000);
        int*   flag    = (int*)  (ws + EOUT + 2600000);
        unsigned char* w1p = (unsigned char*)(ws + EOUT + 2600064);
        unsigned char* w2p = w1p + 262144;

        hipMemsetAsync(denom, 0, 400000, stream);   // denom + count
        init_misc<<<(O_NODES + 255) / 256, 256, 0, stream>>>(mbuf, flag);
        detect_fmt<<<32, 256, 0, stream>>>(pairs, flag);
        detect_dtype<<<1, 64, 0, stream>>>((const unsigned short*)objf, flag);
        edge_max_count<<<(N_EDGES + 255) / 256, 256, 0, stream>>>(pairs, conf, mbuf, count, flag);
        edge_denom<<<(N_EDGES + 255) / 256, 256, 0, stream>>>(pairs, conf, mbuf, denom, flag);
        scan50k<<<1, SCAN_T, 0, stream>>>(count, offsets, cursor);
        scatter_inc<<<(N_EDGES + 255) / 256, 256, 0, stream>>>(pairs, cursor, inc, flag);
        repack_w2<<<2048, 256, 0, stream>>>(W1, W2, w1p, w2p, flag);

        fused_mlp<1><<<N_EDGES / ET, 512, lds, stream>>>(
            objf, pairs, conf, w1p, b1, w2p, b2, mbuf, (float*)nullptr, edgeout, flag);

        node_gather<<<(O_NODES + 3) / 4, 256, 0, stream>>>(
            (const unsigned*)edgeout, inc, offsets, count, denom, mbuf, conf, objf, d_out, flag);
    } else {
        float* numer = (float*)ws;                              // 12.8M f32
        float* denom = numer + (size_t)O_NODES * DD;
        float* mbuf  = denom + O_NODES;
        int*   count = (int*)(mbuf + O_NODES);                  // scratch (unused sums ok)
        int*   flag  = count + O_NODES;
        unsigned char* w1p = (unsigned char*)(flag + 16);
        unsigned char* w2p = w1p + 262144;

        hipMemsetAsync(numer, 0, (size_t)(O_NODES * DD + 2 * O_NODES) * sizeof(float), stream);
        init_misc<<<(O_NODES + 255) / 256, 256, 0, stream>>>(mbuf, flag);
        detect_fmt<<<32, 256, 0, stream>>>(pairs, flag);
        detect_dtype<<<1, 64, 0, stream>>>((const unsigned short*)objf, flag);
        edge_max_count<<<(N_EDGES + 255) / 256, 256, 0, stream>>>(pairs, conf, mbuf, count, flag);
        edge_denom<<<(N_EDGES + 255) / 256, 256, 0, stream>>>(pairs, conf, mbuf, denom, flag);
        repack_w2<<<2048, 256, 0, stream>>>(W1, W2, w1p, w2p, flag);

        fused_mlp<0><<<N_EDGES / ET, 512, lds, stream>>>(
            objf, pairs, conf, w1p, b1, w2p, b2, mbuf, numer, (unsigned char*)nullptr, flag);

        finalize_k<<<(O_NODES * DD / 4 + 255) / 256, 256, 0, stream>>>(numer, denom, mbuf, objf, d_out, flag);
    }
}

// Round 6
// 520.004 us; speedup vs baseline: 1.5466x; 1.2063x over previous
//
#include <hip/hip_runtime.h>
#include <hip/hip_bf16.h>
#include <hip/hip_fp8.h>

#define O_NODES 50000
#define N_EDGES 200000
#define DD 256
#define KDIM 512
#define NDIM 512
#define ET 64           // edges per block; 200000 % 64 == 0 -> all tiles full
#define LDSF8 528       // padded fp8 LDS row stride (512 + 16; 16B-aligned rows)

typedef float f32x4 __attribute__((ext_vector_type(4)));

// ---------- fp8 e4m3 helpers ----------
__device__ __forceinline__ unsigned pack4_fp8(float a, float b, float c, float d) {
#if __has_builtin(__builtin_amdgcn_cvt_pk_fp8_f32)
    int v = __builtin_amdgcn_cvt_pk_fp8_f32(a, b, 0, false);
    v = __builtin_amdgcn_cvt_pk_fp8_f32(c, d, v, true);
    return (unsigned)v;
#else
    __hip_fp8_e4m3 x(a), y(b), z(c), w(d);
    return (unsigned)x.__x | ((unsigned)y.__x << 8) | ((unsigned)z.__x << 16) | ((unsigned)w.__x << 24);
#endif
}

__device__ __forceinline__ unsigned char f2fp8(float x) {
#if __has_builtin(__builtin_amdgcn_cvt_pk_fp8_f32)
    return (unsigned char)(__builtin_amdgcn_cvt_pk_fp8_f32(x, x, 0, false) & 0xff);
#else
    __hip_fp8_e4m3 t(x); return t.__x;
#endif
}

__device__ __forceinline__ f32x4 unpack4_fp8(unsigned v) {
#if __has_builtin(__builtin_amdgcn_cvt_pk_f32_fp8)
    auto lo = __builtin_amdgcn_cvt_pk_f32_fp8((int)v, false);
    auto hi = __builtin_amdgcn_cvt_pk_f32_fp8((int)v, true);
    return (f32x4){lo[0], lo[1], hi[0], hi[1]};
#else
    __hip_fp8_e4m3 t0, t1, t2, t3;
    t0.__x = v & 0xff; t1.__x = (v >> 8) & 0xff; t2.__x = (v >> 16) & 0xff; t3.__x = (v >> 24) & 0xff;
    return (f32x4){(float)t0, (float)t1, (float)t2, (float)t3};
#endif
}

__device__ __forceinline__ f32x4 mfma_fp8(long a, long b, f32x4 c) {
    return __builtin_amdgcn_mfma_f32_16x16x32_fp8_fp8(a, b, c, 0, 0, 0);
}

// ---------- generic input helpers ----------
__device__ __forceinline__ int get_pair(const int* __restrict__ p, long e, int which, int is32) {
    // is32: [sub0,obj0,...]; int64 case: [sub0,0,obj0,0,...] viewed as int32
    return is32 ? p[2 * e + which] : p[4 * e + 2 * which];
}

__device__ __forceinline__ float load_f(const void* p, long i, int is_f32) {
    if (is_f32) return ((const float*)p)[i];
    unsigned short u = ((const unsigned short*)p)[i];
    return __uint_as_float((unsigned)u << 16);
}

__device__ __forceinline__ float bf2f(unsigned short u) {
    return __uint_as_float((unsigned)u << 16);
}

// flag[0] = pairs-are-int32, flag[1] = floats-are-f32
__global__ void init_misc(float* mbuf, int* flag) {
    int i = blockIdx.x * 256 + threadIdx.x;
    if (i < O_NODES) mbuf[i] = 10.0f;
    if (i == 0) { flag[0] = 0; }
}

__global__ void detect_fmt(const int* __restrict__ pairs, int* flag) {
    int i = blockIdx.x * 256 + threadIdx.x;   // 8192 probes
    if (pairs[2 * i + 1] != 0) flag[0] = 1;
}

__global__ void detect_dtype(const unsigned short* __restrict__ w, int* flag) {
    // bf16 data: low half of each 32b word is a bf16 N(0,1) draw -> |v| in [0.004,16] w.p. ~99%
    // f32 data: low half is mantissa noise -> in range w.p. ~4%
    int lane = threadIdx.x & 63;
    unsigned short u = w[2 * lane];
    float v = fabsf(__uint_as_float((unsigned)u << 16));
    bool in_range = (v > 0.004f && v < 16.0f);
    unsigned long long m = __ballot(in_range);
    if (lane == 0) flag[1] = (__popcll(m) < 32) ? 1 : 0;
}

// pre-convert object_feats to fp8: 50000 x 256 -> 12.8 MB (4x less gather traffic)
__global__ void cvt_objf(const void* __restrict__ objf, unsigned* __restrict__ objf8,
                         const int* __restrict__ flag) {
    int i4 = blockIdx.x * 256 + threadIdx.x;   // < 3,200,000
    if (i4 >= O_NODES * DD / 4) return;
    int isf = flag[1];
    float x0, x1, x2, x3;
    if (isf) {
        float4 v = ((const float4*)objf)[i4];
        x0 = v.x; x1 = v.y; x2 = v.z; x3 = v.w;
    } else {
        ushort4 u = ((const ushort4*)objf)[i4];
        x0 = bf2f(u.x); x1 = bf2f(u.y); x2 = bf2f(u.z); x3 = bf2f(u.w);
    }
    objf8[i4] = pack4_fp8(x0, x1, x2, x3);
}

// max + degree histogram in one pass (count doesn't depend on max)
__global__ void edge_max_count(const int* __restrict__ pairs, const void* __restrict__ conf,
                               float* mbuf, int* count, const int* __restrict__ flag) {
    int i = blockIdx.x * 256 + threadIdx.x;
    if (i >= N_EDGES) return;
    int is32 = flag[0], isf = flag[1];
    int s = get_pair(pairs, i, 0, is32);
    int o = get_pair(pairs, i, 1, is32);
    float c = load_f(conf, i, isf);
    int cb = __float_as_int(c);
    // mbuf init = 10.0f (positive) -> signed-int atomicMax is order-correct
    atomicMax((int*)&mbuf[s], cb);
    atomicMax((int*)&mbuf[o], cb);
    atomicAdd(&count[s], 1);
    atomicAdd(&count[o], 1);
}

__global__ void edge_denom(const int* __restrict__ pairs, const void* __restrict__ conf,
                           const float* __restrict__ mbuf, float* denom, const int* __restrict__ flag) {
    int i = blockIdx.x * 256 + threadIdx.x;
    if (i >= N_EDGES) return;
    int is32 = flag[0], isf = flag[1];
    int s = get_pair(pairs, i, 0, is32);
    int o = get_pair(pairs, i, 1, is32);
    float c = load_f(conf, i, isf);
    atomicAdd(&denom[s], __expf(c - mbuf[s]));
    atomicAdd(&denom[o], __expf(c - mbuf[o]));
}

// coalesced single-block scan: tiles of 1024, wave shfl-scan + cross-wave combine
#define SCAN_T 1024
__global__ __launch_bounds__(SCAN_T) void scan50k(const int* __restrict__ count,
                                                  int* __restrict__ offsets,
                                                  int* __restrict__ cursor) {
    __shared__ int wsum[16];
    __shared__ int carry_s;
    int t = threadIdx.x;
    int lane = t & 63, wid = t >> 6;
    if (t == 0) carry_s = 0;
    __syncthreads();
    for (int base = 0; base < O_NODES; base += SCAN_T) {
        int i = base + t;
        int c = (i < O_NODES) ? count[i] : 0;
        int v = c;
        #pragma unroll
        for (int d = 1; d < 64; d <<= 1) {
            int u = __shfl_up(v, d, 64);
            if (lane >= d) v += u;
        }
        if (lane == 63) wsum[wid] = v;
        __syncthreads();
        if (wid == 0) {
            int s = (lane < 16) ? wsum[lane] : 0;
            #pragma unroll
            for (int d = 1; d < 16; d <<= 1) {
                int u = __shfl_up(s, d, 64);
                if (lane >= d) s += u;
            }
            if (lane < 16) wsum[lane] = s;
        }
        __syncthreads();
        int wprefix = (wid == 0) ? 0 : wsum[wid - 1];
        int excl = carry_s + wprefix + v - c;
        if (i < O_NODES) { offsets[i] = excl; cursor[i] = excl; }
        int total = wsum[15];
        __syncthreads();
        if (t == 0) carry_s += total;
        __syncthreads();
    }
}

// incidence scatter: inc entry = edge*2 + half  (half 0 = sub part, 1 = obj part)
__global__ void scatter_inc(const int* __restrict__ pairs, int* __restrict__ cursor,
                            int* __restrict__ inc, const int* __restrict__ flag) {
    int i = blockIdx.x * 256 + threadIdx.x;
    if (i >= N_EDGES) return;
    int is32 = flag[0];
    int s = get_pair(pairs, i, 0, is32);
    int o = get_pair(pairs, i, 1, is32);
    int ps = atomicAdd(&cursor[s], 1);
    inc[ps] = 2 * i;
    int po = atomicAdd(&cursor[o], 1);
    inc[po] = 2 * i + 1;
}

// Pack both W (512x512 row-major) into fp8 MFMA-B-fragment order:
// byte idx ((tk*32+tn)*64 + lane)*8 + j holds B[tk*32 + (lane>>4)*8 + j][tn*16 + (lane&15)]
__global__ void repack_w2(const void* __restrict__ W1, const void* __restrict__ W2,
                          unsigned char* __restrict__ Wp1, unsigned char* __restrict__ Wp2,
                          const int* __restrict__ flag) {
    int b = blockIdx.x;
    const void* W = (b < 1024) ? W1 : W2;
    unsigned char* Wp = (b < 1024) ? Wp1 : Wp2;
    int idx = ((b & 1023) << 8) + threadIdx.x;   // < 262144
    int isf = flag[1];
    int j  = idx & 7;
    int l  = (idx >> 3) & 63;
    int tn = (idx >> 9) & 31;
    int tk = idx >> 14;
    int k = tk * 32 + (l >> 4) * 8 + j;
    int n = tn * 16 + (l & 15);
    Wp[idx] = f2fp8(load_f(W, (long)k * NDIM + n, isf));
}

// CSR=1: stream UNWEIGHTED per-edge outputs (fp8) to edgeout
// CSR=0: weighted f32 atomicAdd into numer (fallback)
template<int CSR>
__global__ __launch_bounds__(512, 2) void fused_mlp(
    const unsigned* __restrict__ objf8,
    const int* __restrict__ pairs,
    const void* __restrict__ conf,
    const unsigned char* __restrict__ w1p,
    const void* __restrict__ b1,
    const unsigned char* __restrict__ w2p,
    const void* __restrict__ b2,
    const float* __restrict__ mbuf,
    float* __restrict__ numer,
    unsigned char* __restrict__ edgeout,
    const int* __restrict__ flag)
{
    extern __shared__ char smem[];
    unsigned char* sA    = (unsigned char*)smem;           // ET x LDSF8 fp8
    int*           sNode = (int*)(smem + ET * LDSF8);      // [2][ET]
    float*         sW    = (float*)(smem + ET * LDSF8 + 2 * ET * 4); // [2][ET]

    const int tid  = threadIdx.x;
    const int wave = tid >> 6;      // 0..7
    const int lane = tid & 63;
    const int l15  = lane & 15;
    const int lq   = lane >> 4;
    const long blockStart = (long)blockIdx.x * ET;
    const int is32 = flag[0];
    const int isf  = flag[1];

    // per-edge metadata (all tiles full: 200000 % 64 == 0)
    if (tid < ET) {
        long e = blockStart + tid;
        int s = get_pair(pairs, e, 0, is32);
        int o = get_pair(pairs, e, 1, is32);
        sNode[tid] = s; sNode[ET + tid] = o;
        if constexpr (!CSR) {
            float c = load_f(conf, e, isf);
            sW[tid]      = __expf(c - mbuf[s]);
            sW[ET + tid] = __expf(c - mbuf[o]);
        }
    }
    __syncthreads();

    // gather concat feats (pre-converted fp8) -> LDS: row e = [objf8[sub] | objf8[obj]]
    // 64 rows x 128 uint-groups = 8192; 16 per thread; pure uint copy
    #pragma unroll
    for (int it = 0; it < 16; ++it) {
        int idx = it * 512 + tid;
        int row = idx >> 7;
        int g   = idx & 127;
        int node = sNode[(g >> 6) * ET + row];
        unsigned v = objf8[(long)node * 64 + (g & 63)];
        *(unsigned*)(sA + row * LDSF8 + g * 4) = v;
    }
    __syncthreads();

    const int nw = wave * 64;   // wave's n base; tn = wave*4 + nt
    f32x4 acc[4][4];
    #pragma unroll
    for (int mt = 0; mt < 4; ++mt)
        #pragma unroll
        for (int nt = 0; nt < 4; ++nt)
            acc[mt][nt] = (f32x4){0.f, 0.f, 0.f, 0.f};

    // ---- GEMM1: h = feats @ W1 (fp8) ----
    {
        const long* bq = (const long*)w1p;
        for (int tk = 0; tk < 16; ++tk) {
            long a[4];
            #pragma unroll
            for (int mt = 0; mt < 4; ++mt)
                a[mt] = *(const long*)(sA + (mt * 16 + l15) * LDSF8 + tk * 32 + lq * 8);
            #pragma unroll
            for (int nt = 0; nt < 4; ++nt) {
                long b = bq[(tk * 32 + wave * 4 + nt) * 64 + lane];
                #pragma unroll
                for (int mt = 0; mt < 4; ++mt)
                    acc[mt][nt] = mfma_fp8(a[mt], b, acc[mt][nt]);
            }
        }
    }
    __syncthreads();

    // bias + relu, h (fp8) back into sA
    #pragma unroll
    for (int nt = 0; nt < 4; ++nt) {
        int n = nw + nt * 16 + l15;
        float bias = load_f(b1, n, isf);
        #pragma unroll
        for (int mt = 0; mt < 4; ++mt) {
            #pragma unroll
            for (int r = 0; r < 4; ++r) {
                int mrow = mt * 16 + lq * 4 + r;
                sA[mrow * LDSF8 + n] = f2fp8(fmaxf(acc[mt][nt][r] + bias, 0.f));
            }
        }
    }
    __syncthreads();

    // ---- GEMM2: out = h @ W2 (fp8) ----
    #pragma unroll
    for (int mt = 0; mt < 4; ++mt)
        #pragma unroll
        for (int nt = 0; nt < 4; ++nt)
            acc[mt][nt] = (f32x4){0.f, 0.f, 0.f, 0.f};
    {
        const long* bq = (const long*)w2p;
        for (int tk = 0; tk < 16; ++tk) {
            long a[4];
            #pragma unroll
            for (int mt = 0; mt < 4; ++mt)
                a[mt] = *(const long*)(sA + (mt * 16 + l15) * LDSF8 + tk * 32 + lq * 8);
            #pragma unroll
            for (int nt = 0; nt < 4; ++nt) {
                long b = bq[(tk * 32 + wave * 4 + nt) * 64 + lane];
                #pragma unroll
                for (int mt = 0; mt < 4; ++mt)
                    acc[mt][nt] = mfma_fp8(a[mt], b, acc[mt][nt]);
            }
        }
    }

    if constexpr (CSR) {
        // unweighted out (fp8) -> sA -> coalesced stream
        __syncthreads();
        float bias2[4];
        #pragma unroll
        for (int nt = 0; nt < 4; ++nt)
            bias2[nt] = load_f(b2, nw + nt * 16 + l15, isf);
        #pragma unroll
        for (int nt = 0; nt < 4; ++nt) {
            int n = nw + nt * 16 + l15;
            #pragma unroll
            for (int mt = 0; mt < 4; ++mt) {
                #pragma unroll
                for (int r = 0; r < 4; ++r) {
                    int mrow = mt * 16 + lq * 4 + r;
                    sA[mrow * LDSF8 + n] = f2fp8(acc[mt][nt][r] + bias2[nt]);
                }
            }
        }
        __syncthreads();
        // stream: 64 rows x 32 uint4 = 2048; 4 per thread
        #pragma unroll
        for (int it = 0; it < 4; ++it) {
            int idx = it * 512 + tid;
            int row = idx >> 5;
            int ch  = idx & 31;
            uint4 v = *(const uint4*)(sA + row * LDSF8 + ch * 16);
            ((uint4*)edgeout)[(blockStart + row) * 32 + ch] = v;
        }
    } else {
        // fallback: weighted f32 atomic scatter
        const int half  = wave >> 2;
        const int cbase = nw - half * 256;
        float bias2[4];
        #pragma unroll
        for (int nt = 0; nt < 4; ++nt)
            bias2[nt] = load_f(b2, nw + nt * 16 + l15, isf);
        #pragma unroll
        for (int mt = 0; mt < 4; ++mt) {
            #pragma unroll
            for (int r = 0; r < 4; ++r) {
                int mrow = mt * 16 + lq * 4 + r;
                int   node = sNode[half * ET + mrow];
                float w    = sW[half * ET + mrow];
                float* nrow = numer + (long)node * DD + cbase;
                #pragma unroll
                for (int nt = 0; nt < 4; ++nt)
                    atomicAdd(nrow + nt * 16 + l15, w * (acc[mt][nt][r] + bias2[nt]));
            }
        }
    }
}

// one wave per node: weighted sum of fp8 incidence half-rows (unroll 8), self term, divide
__global__ __launch_bounds__(256) void node_gather(
    const unsigned* __restrict__ edgeout,   // uint view; edge row = 128 uints
    const int* __restrict__ inc,
    const int* __restrict__ offsets,
    const int* __restrict__ count,
    const float* __restrict__ denom,
    const float* __restrict__ mbuf,
    const void* __restrict__ conf,
    const void* __restrict__ objf,
    void* __restrict__ out,
    const int* __restrict__ flag)
{
    int nid  = blockIdx.x * 4 + (threadIdx.x >> 6);
    if (nid >= O_NODES) return;
    int lane = threadIdx.x & 63;
    int isf  = flag[1];

    int off = offsets[nid];
    int deg = count[nid];
    float mnode = mbuf[nid];

    // per-lane precompute of incidence id + weight
    int j = 0; float wg = 0.f;
    if (lane < deg) {
        j  = inc[off + lane];
        wg = __expf(load_f(conf, j >> 1, isf) - mnode);
    }

    float a0 = 0.f, a1 = 0.f, a2 = 0.f, a3 = 0.f;
    int m  = deg < 64 ? deg : 64;
    int m8 = m & ~7;
    int i = 0;
    for (; i < m8; i += 8) {
        unsigned v[8]; float w[8];
        #pragma unroll
        for (int k = 0; k < 8; ++k) {
            int   jj = __shfl(j, i + k, 64);
            w[k] = __shfl(wg, i + k, 64);
            v[k] = edgeout[(long)(jj >> 1) * 128 + (jj & 1) * 64 + lane];
        }
        #pragma unroll
        for (int k = 0; k < 8; ++k) {
            f32x4 f = unpack4_fp8(v[k]);
            a0 += w[k] * f[0]; a1 += w[k] * f[1]; a2 += w[k] * f[2]; a3 += w[k] * f[3];
        }
    }
    for (; i < m; ++i) {
        int   jj = __shfl(j, i, 64);
        float ww = __shfl(wg, i, 64);
        unsigned v = edgeout[(long)(jj >> 1) * 128 + (jj & 1) * 64 + lane];
        f32x4 f = unpack4_fp8(v);
        a0 += ww * f[0]; a1 += ww * f[1]; a2 += ww * f[2]; a3 += ww * f[3];
    }
    for (int idx = off + 64; idx < off + deg; ++idx) {   // rare deg > 64
        int jj = inc[idx];
        float ww = __expf(load_f(conf, jj >> 1, isf) - mnode);
        unsigned v = edgeout[(long)(jj >> 1) * 128 + (jj & 1) * 64 + lane];
        f32x4 f = unpack4_fp8(v);
        a0 += ww * f[0]; a1 += ww * f[1]; a2 += ww * f[2]; a3 += ww * f[3];
    }

    float sw  = __expf(10.0f - mnode);
    float inv = 1.0f / (denom[nid] + sw);
    float o0, o1, o2, o3;
    if (isf) {
        float4 ov = ((const float4*)objf)[(long)nid * 64 + lane];
        o0 = ov.x; o1 = ov.y; o2 = ov.z; o3 = ov.w;
    } else {
        ushort4 ou = ((const ushort4*)objf)[(long)nid * 64 + lane];
        o0 = bf2f(ou.x); o1 = bf2f(ou.y); o2 = bf2f(ou.z); o3 = bf2f(ou.w);
    }
    float r0 = (a0 + sw * o0) * inv;
    float r1 = (a1 + sw * o1) * inv;
    float r2 = (a2 + sw * o2) * inv;
    float r3 = (a3 + sw * o3) * inv;
    if (isf) {
        float4 rv = { r0, r1, r2, r3 };
        ((float4*)out)[(long)nid * 64 + lane] = rv;
    } else {
        __hip_bfloat16 h0 = __float2bfloat16(r0);
        __hip_bfloat16 h1 = __float2bfloat16(r1);
        __hip_bfloat16 h2 = __float2bfloat16(r2);
        __hip_bfloat16 h3 = __float2bfloat16(r3);
        ushort4 ru;
        ru.x = *(unsigned short*)&h0;
        ru.y = *(unsigned short*)&h1;
        ru.z = *(unsigned short*)&h2;
        ru.w = *(unsigned short*)&h3;
        ((ushort4*)out)[(long)nid * 64 + lane] = ru;
    }
}

// fallback finalize (f32 numer)
__global__ void finalize_k(const float* __restrict__ numer, const float* __restrict__ denom,
                           const float* __restrict__ mbuf, const void* __restrict__ objf,
                           void* __restrict__ out, const int* __restrict__ flag) {
    long i4 = (long)blockIdx.x * 256 + threadIdx.x;
    if (i4 >= (long)O_NODES * DD / 4) return;
    int isf = flag[1];
    long base = i4 * 4;
    int node = (int)(base >> 8);
    float sw  = __expf(10.0f - mbuf[node]);
    float inv = 1.0f / (denom[node] + sw);
    f32x4 nm = *(const f32x4*)(numer + base);
    float o0, o1, o2, o3;
    if (isf) {
        float4 ov = ((const float4*)objf)[i4];
        o0 = ov.x; o1 = ov.y; o2 = ov.z; o3 = ov.w;
    } else {
        ushort4 ou = ((const ushort4*)objf)[i4];
        o0 = bf2f(ou.x); o1 = bf2f(ou.y); o2 = bf2f(ou.z); o3 = bf2f(ou.w);
    }
    float r0 = (nm[0] + sw * o0) * inv;
    float r1 = (nm[1] + sw * o1) * inv;
    float r2 = (nm[2] + sw * o2) * inv;
    float r3 = (nm[3] + sw * o3) * inv;
    if (isf) {
        float4 rv = { r0, r1, r2, r3 };
        ((float4*)out)[i4] = rv;
    } else {
        __hip_bfloat16 h0 = __float2bfloat16(r0);
        __hip_bfloat16 h1 = __float2bfloat16(r1);
        __hip_bfloat16 h2 = __float2bfloat16(r2);
        __hip_bfloat16 h3 = __float2bfloat16(r3);
        ushort4 ru;
        ru.x = *(unsigned short*)&h0;
        ru.y = *(unsigned short*)&h1;
        ru.z = *(unsigned short*)&h2;
        ru.w = *(unsigned short*)&h3;
        ((ushort4*)out)[i4] = ru;
    }
}

extern "C" void kernel_launch(void* const* d_in, const int* in_sizes, int n_in,
                              void* d_out, int out_size, void* d_ws, size_t ws_size,
                              hipStream_t stream) {
    const void* objf  = d_in[0];
    const int*  pairs = (const int*)d_in[1];
    const void* conf  = d_in[2];
    const void* W1    = d_in[3];
    const void* b1    = d_in[4];
    const void* W2    = d_in[5];
    const void* b2    = d_in[6];

    const size_t EOUT  = (size_t)N_EDGES * 512;             // 102,400,000 B (fp8)
    const size_t OBJ8  = (size_t)O_NODES * DD;              // 12,800,000 B (fp8)
    const size_t need_csr = EOUT + 2600064 + 2 * 262144 + OBJ8;
    char* ws = (char*)d_ws;
    size_t lds = (size_t)ET * LDSF8 + 4 * ET * 4;           // 34816 B

    if (ws_size >= need_csr) {
        unsigned char* edgeout = (unsigned char*)ws;
        float* denom   = (float*)(ws + EOUT);
        int*   count   = (int*)  (ws + EOUT + 200000);
        float* mbuf    = (float*)(ws + EOUT + 400000);
        int*   offsets = (int*)  (ws + EOUT + 600000);
        int*   cursor  = (int*)  (ws + EOUT + 800000);
        int*   inc     = (int*)  (ws + EOUT + 1000000);
        int*   flag    = (int*)  (ws + EOUT + 2600000);
        unsigned char* w1p = (unsigned char*)(ws + EOUT + 2600064);
        unsigned char* w2p = w1p + 262144;
        unsigned* objf8 = (unsigned*)(w2p + 262144);

        hipMemsetAsync(denom, 0, 400000, stream);   // denom + count
        init_misc<<<(O_NODES + 255) / 256, 256, 0, stream>>>(mbuf, flag);
        detect_fmt<<<32, 256, 0, stream>>>(pairs, flag);
        detect_dtype<<<1, 64, 0, stream>>>((const unsigned short*)objf, flag);
        cvt_objf<<<(O_NODES * DD / 4 + 255) / 256, 256, 0, stream>>>(objf, objf8, flag);
        edge_max_count<<<(N_EDGES + 255) / 256, 256, 0, stream>>>(pairs, conf, mbuf, count, flag);
        edge_denom<<<(N_EDGES + 255) / 256, 256, 0, stream>>>(pairs, conf, mbuf, denom, flag);
        scan50k<<<1, SCAN_T, 0, stream>>>(count, offsets, cursor);
        scatter_inc<<<(N_EDGES + 255) / 256, 256, 0, stream>>>(pairs, cursor, inc, flag);
        repack_w2<<<2048, 256, 0, stream>>>(W1, W2, w1p, w2p, flag);

        fused_mlp<1><<<N_EDGES / ET, 512, lds, stream>>>(
            objf8, pairs, conf, w1p, b1, w2p, b2, mbuf, (float*)nullptr, edgeout, flag);

        node_gather<<<(O_NODES + 3) / 4, 256, 0, stream>>>(
            (const unsigned*)edgeout, inc, offsets, count, denom, mbuf, conf, objf, d_out, flag);
    } else {
        float* numer = (float*)ws;                              // 12.8M f32
        float* denom = numer + (size_t)O_NODES * DD;
        float* mbuf  = denom + O_NODES;
        int*   count = (int*)(mbuf + O_NODES);                  // scratch
        int*   flag  = count + O_NODES;
        unsigned char* w1p = (unsigned char*)(flag + 16);
        unsigned char* w2p = w1p + 262144;
        unsigned* objf8 = (unsigned*)(w2p + 262144);

        hipMemsetAsync(numer, 0, (size_t)(O_NODES * DD + 2 * O_NODES) * sizeof(float), stream);
        init_misc<<<(O_NODES + 255) / 256, 256, 0, stream>>>(mbuf, flag);
        detect_fmt<<<32, 256, 0, stream>>>(pairs, flag);
        detect_dtype<<<1, 64, 0, stream>>>((const unsigned short*)objf, flag);
        cvt_objf<<<(O_NODES * DD / 4 + 255) / 256, 256, 0, stream>>>(objf, objf8, flag);
        edge_max_count<<<(N_EDGES + 255) / 256, 256, 0, stream>>>(pairs, conf, mbuf, count, flag);
        edge_denom<<<(N_EDGES + 255) / 256, 256, 0, stream>>>(pairs, conf, mbuf, denom, flag);
        repack_w2<<<2048, 256, 0, stream>>>(W1, W2, w1p, w2p, flag);

        fused_mlp<0><<<N_EDGES / ET, 512, lds, stream>>>(
            objf8, pairs, conf, w1p, b1, w2p, b2, mbuf, numer, (unsigned char*)nullptr, flag);

        finalize_k<<<(O_NODES * DD / 4 + 255) / 256, 256, 0, stream>>>(numer, denom, mbuf, objf, d_out, flag);
    }
}

// Round 7
// 495.447 us; speedup vs baseline: 1.6232x; 1.0496x over previous
//
#include <hip/hip_runtime.h>
#include <hip/hip_bf16.h>
#include <hip/hip_fp8.h>

#define O_NODES 50000
#define N_EDGES 200000
#define DD 256
#define KDIM 512
#define NDIM 512
#define ET 32           // edges per block; small tile -> 32 acc regs -> 2 blocks/CU
#define LDSF8 528       // padded fp8 LDS row stride

typedef float f32x4 __attribute__((ext_vector_type(4)));

// ---------- fp8 e4m3 helpers ----------
__device__ __forceinline__ unsigned pack4_fp8(float a, float b, float c, float d) {
#if __has_builtin(__builtin_amdgcn_cvt_pk_fp8_f32)
    int v = __builtin_amdgcn_cvt_pk_fp8_f32(a, b, 0, false);
    v = __builtin_amdgcn_cvt_pk_fp8_f32(c, d, v, true);
    return (unsigned)v;
#else
    __hip_fp8_e4m3 x(a), y(b), z(c), w(d);
    return (unsigned)x.__x | ((unsigned)y.__x << 8) | ((unsigned)z.__x << 16) | ((unsigned)w.__x << 24);
#endif
}

__device__ __forceinline__ unsigned char f2fp8(float x) {
#if __has_builtin(__builtin_amdgcn_cvt_pk_fp8_f32)
    return (unsigned char)(__builtin_amdgcn_cvt_pk_fp8_f32(x, x, 0, false) & 0xff);
#else
    __hip_fp8_e4m3 t(x); return t.__x;
#endif
}

__device__ __forceinline__ f32x4 unpack4_fp8(unsigned v) {
#if __has_builtin(__builtin_amdgcn_cvt_pk_f32_fp8)
    auto lo = __builtin_amdgcn_cvt_pk_f32_fp8((int)v, false);
    auto hi = __builtin_amdgcn_cvt_pk_f32_fp8((int)v, true);
    return (f32x4){lo[0], lo[1], hi[0], hi[1]};
#else
    __hip_fp8_e4m3 t0, t1, t2, t3;
    t0.__x = v & 0xff; t1.__x = (v >> 8) & 0xff; t2.__x = (v >> 16) & 0xff; t3.__x = (v >> 24) & 0xff;
    return (f32x4){(float)t0, (float)t1, (float)t2, (float)t3};
#endif
}

__device__ __forceinline__ f32x4 mfma_fp8(long a, long b, f32x4 c) {
    return __builtin_amdgcn_mfma_f32_16x16x32_fp8_fp8(a, b, c, 0, 0, 0);
}

// ---------- generic input helpers ----------
__device__ __forceinline__ int get_pair(const int* __restrict__ p, long e, int which, int is32) {
    return is32 ? p[2 * e + which] : p[4 * e + 2 * which];
}

__device__ __forceinline__ float load_f(const void* p, long i, int is_f32) {
    if (is_f32) return ((const float*)p)[i];
    unsigned short u = ((const unsigned short*)p)[i];
    return __uint_as_float((unsigned)u << 16);
}

__device__ __forceinline__ float bf2f(unsigned short u) {
    return __uint_as_float((unsigned)u << 16);
}

// flag[0] = pairs-are-int32, flag[1] = floats-are-f32  (flag pre-zeroed by memset)
__global__ void init_all(const int* __restrict__ pairs, const unsigned short* __restrict__ w,
                         float* mbuf, int* flag) {
    int i = blockIdx.x * 256 + threadIdx.x;
    if (i < O_NODES) mbuf[i] = 10.0f;
    if (i < 8192 && pairs[2 * i + 1] != 0) flag[0] = 1;   // int64 high words all zero
    if (blockIdx.x == 0 && threadIdx.x < 64) {
        // dtype probe: low 16-bit halves of first 64 words; bf16 pairs decode in-range ~99%
        int lane = threadIdx.x;
        unsigned short u = w[2 * lane];
        float v = fabsf(__uint_as_float((unsigned)u << 16));
        bool in_range = (v > 0.004f && v < 16.0f);
        unsigned long long m = __ballot(in_range);
        if (lane == 0) flag[1] = (__popcll(m) < 32) ? 1 : 0;
    }
}

// pre-convert object_feats to fp8: 50000 x 256 -> 12.8 MB
__global__ void cvt_objf(const void* __restrict__ objf, unsigned* __restrict__ objf8,
                         const int* __restrict__ flag) {
    int i4 = blockIdx.x * 256 + threadIdx.x;
    if (i4 >= O_NODES * DD / 4) return;
    int isf = flag[1];
    float x0, x1, x2, x3;
    if (isf) {
        float4 v = ((const float4*)objf)[i4];
        x0 = v.x; x1 = v.y; x2 = v.z; x3 = v.w;
    } else {
        ushort4 u = ((const ushort4*)objf)[i4];
        x0 = bf2f(u.x); x1 = bf2f(u.y); x2 = bf2f(u.z); x3 = bf2f(u.w);
    }
    objf8[i4] = pack4_fp8(x0, x1, x2, x3);
}

// max + degree histogram
__global__ void edge_max_count(const int* __restrict__ pairs, const void* __restrict__ conf,
                               float* mbuf, int* count, const int* __restrict__ flag) {
    int i = blockIdx.x * 256 + threadIdx.x;
    if (i >= N_EDGES) return;
    int is32 = flag[0], isf = flag[1];
    int s = get_pair(pairs, i, 0, is32);
    int o = get_pair(pairs, i, 1, is32);
    float c = load_f(conf, i, isf);
    int cb = __float_as_int(c);
    atomicMax((int*)&mbuf[s], cb);   // mbuf init 10.0f > 0 -> int max order-correct
    atomicMax((int*)&mbuf[o], cb);
    atomicAdd(&count[s], 1);
    atomicAdd(&count[o], 1);
}

// fallback-only denom
__global__ void edge_denom(const int* __restrict__ pairs, const void* __restrict__ conf,
                           const float* __restrict__ mbuf, float* denom, const int* __restrict__ flag) {
    int i = blockIdx.x * 256 + threadIdx.x;
    if (i >= N_EDGES) return;
    int is32 = flag[0], isf = flag[1];
    int s = get_pair(pairs, i, 0, is32);
    int o = get_pair(pairs, i, 1, is32);
    float c = load_f(conf, i, isf);
    atomicAdd(&denom[s], __expf(c - mbuf[s]));
    atomicAdd(&denom[o], __expf(c - mbuf[o]));
}

// coalesced single-block scan
#define SCAN_T 1024
__global__ __launch_bounds__(SCAN_T) void scan50k(const int* __restrict__ count,
                                                  int* __restrict__ offsets,
                                                  int* __restrict__ cursor) {
    __shared__ int wsum[16];
    __shared__ int carry_s;
    int t = threadIdx.x;
    int lane = t & 63, wid = t >> 6;
    if (t == 0) carry_s = 0;
    __syncthreads();
    for (int base = 0; base < O_NODES; base += SCAN_T) {
        int i = base + t;
        int c = (i < O_NODES) ? count[i] : 0;
        int v = c;
        #pragma unroll
        for (int d = 1; d < 64; d <<= 1) {
            int u = __shfl_up(v, d, 64);
            if (lane >= d) v += u;
        }
        if (lane == 63) wsum[wid] = v;
        __syncthreads();
        if (wid == 0) {
            int s = (lane < 16) ? wsum[lane] : 0;
            #pragma unroll
            for (int d = 1; d < 16; d <<= 1) {
                int u = __shfl_up(s, d, 64);
                if (lane >= d) s += u;
            }
            if (lane < 16) wsum[lane] = s;
        }
        __syncthreads();
        int wprefix = (wid == 0) ? 0 : wsum[wid - 1];
        int excl = carry_s + wprefix + v - c;
        if (i < O_NODES) { offsets[i] = excl; cursor[i] = excl; }
        int total = wsum[15];
        __syncthreads();
        if (t == 0) carry_s += total;
        __syncthreads();
    }
}

__global__ void scatter_inc(const int* __restrict__ pairs, int* __restrict__ cursor,
                            int* __restrict__ inc, const int* __restrict__ flag) {
    int i = blockIdx.x * 256 + threadIdx.x;
    if (i >= N_EDGES) return;
    int is32 = flag[0];
    int s = get_pair(pairs, i, 0, is32);
    int o = get_pair(pairs, i, 1, is32);
    int ps = atomicAdd(&cursor[s], 1);
    inc[ps] = 2 * i;
    int po = atomicAdd(&cursor[o], 1);
    inc[po] = 2 * i + 1;
}

// Pack both W into fp8 MFMA-B-fragment order:
// byte idx ((tk*32+tn)*64 + lane)*8 + j holds B[tk*32 + (lane>>4)*8 + j][tn*16 + (lane&15)]
__global__ void repack_w2(const void* __restrict__ W1, const void* __restrict__ W2,
                          unsigned char* __restrict__ Wp1, unsigned char* __restrict__ Wp2,
                          const int* __restrict__ flag) {
    int b = blockIdx.x;
    const void* W = (b < 1024) ? W1 : W2;
    unsigned char* Wp = (b < 1024) ? Wp1 : Wp2;
    int idx = ((b & 1023) << 8) + threadIdx.x;
    int isf = flag[1];
    int j  = idx & 7;
    int l  = (idx >> 3) & 63;
    int tn = (idx >> 9) & 31;
    int tk = idx >> 14;
    int k = tk * 32 + (l >> 4) * 8 + j;
    int n = tn * 16 + (l & 15);
    Wp[idx] = f2fp8(load_f(W, (long)k * NDIM + n, isf));
}

// CSR=1: stream UNWEIGHTED per-edge outputs (fp8); CSR=0: weighted f32 atomic fallback
template<int CSR>
__global__ __launch_bounds__(512, 4) void fused_mlp(
    const unsigned* __restrict__ objf8,
    const int* __restrict__ pairs,
    const void* __restrict__ conf,
    const unsigned char* __restrict__ w1p,
    const void* __restrict__ b1,
    const unsigned char* __restrict__ w2p,
    const void* __restrict__ b2,
    const float* __restrict__ mbuf,
    float* __restrict__ numer,
    unsigned char* __restrict__ edgeout,
    const int* __restrict__ flag)
{
    extern __shared__ char smem[];
    unsigned char* sA    = (unsigned char*)smem;           // ET x LDSF8 fp8
    int*           sNode = (int*)(smem + ET * LDSF8);      // [2][ET]
    float*         sW    = (float*)(smem + ET * LDSF8 + 2 * ET * 4); // [2][ET]

    const int tid  = threadIdx.x;
    const int wave = tid >> 6;      // 0..7
    const int lane = tid & 63;
    const int l15  = lane & 15;
    const int lq   = lane >> 4;
    const long blockStart = (long)blockIdx.x * ET;
    const int is32 = flag[0];
    const int isf  = flag[1];

    if (tid < ET) {
        long e = blockStart + tid;
        int s = get_pair(pairs, e, 0, is32);
        int o = get_pair(pairs, e, 1, is32);
        sNode[tid] = s; sNode[ET + tid] = o;
        if constexpr (!CSR) {
            float c = load_f(conf, e, isf);
            sW[tid]      = __expf(c - mbuf[s]);
            sW[ET + tid] = __expf(c - mbuf[o]);
        }
    }
    __syncthreads();

    // gather fp8 rows -> LDS: 32 rows x 128 uints = 4096; 8 per thread
    #pragma unroll
    for (int it = 0; it < 8; ++it) {
        int idx = it * 512 + tid;
        int row = idx >> 7;
        int g   = idx & 127;
        int node = sNode[(g >> 6) * ET + row];
        unsigned v = objf8[(long)node * 64 + (g & 63)];
        *(unsigned*)(sA + row * LDSF8 + g * 4) = v;
    }
    __syncthreads();

    const int nw = wave * 64;   // wave's n base; n-tiles wave*4 + nt
    f32x4 acc[2][4];
    #pragma unroll
    for (int mt = 0; mt < 2; ++mt)
        #pragma unroll
        for (int nt = 0; nt < 4; ++nt)
            acc[mt][nt] = (f32x4){0.f, 0.f, 0.f, 0.f};

    // ---- GEMM1 ----
    {
        const long* bq = (const long*)w1p;
        for (int tk = 0; tk < 16; ++tk) {
            long a[2];
            #pragma unroll
            for (int mt = 0; mt < 2; ++mt)
                a[mt] = *(const long*)(sA + (mt * 16 + l15) * LDSF8 + tk * 32 + lq * 8);
            #pragma unroll
            for (int nt = 0; nt < 4; ++nt) {
                long b = bq[(tk * 32 + wave * 4 + nt) * 64 + lane];
                #pragma unroll
                for (int mt = 0; mt < 2; ++mt)
                    acc[mt][nt] = mfma_fp8(a[mt], b, acc[mt][nt]);
            }
        }
    }
    __syncthreads();

    // bias + relu -> fp8 back to sA
    #pragma unroll
    for (int nt = 0; nt < 4; ++nt) {
        int n = nw + nt * 16 + l15;
        float bias = load_f(b1, n, isf);
        #pragma unroll
        for (int mt = 0; mt < 2; ++mt) {
            #pragma unroll
            for (int r = 0; r < 4; ++r) {
                int mrow = mt * 16 + lq * 4 + r;
                sA[mrow * LDSF8 + n] = f2fp8(fmaxf(acc[mt][nt][r] + bias, 0.f));
            }
        }
    }
    __syncthreads();

    // ---- GEMM2 ----
    #pragma unroll
    for (int mt = 0; mt < 2; ++mt)
        #pragma unroll
        for (int nt = 0; nt < 4; ++nt)
            acc[mt][nt] = (f32x4){0.f, 0.f, 0.f, 0.f};
    {
        const long* bq = (const long*)w2p;
        for (int tk = 0; tk < 16; ++tk) {
            long a[2];
            #pragma unroll
            for (int mt = 0; mt < 2; ++mt)
                a[mt] = *(const long*)(sA + (mt * 16 + l15) * LDSF8 + tk * 32 + lq * 8);
            #pragma unroll
            for (int nt = 0; nt < 4; ++nt) {
                long b = bq[(tk * 32 + wave * 4 + nt) * 64 + lane];
                #pragma unroll
                for (int mt = 0; mt < 2; ++mt)
                    acc[mt][nt] = mfma_fp8(a[mt], b, acc[mt][nt]);
            }
        }
    }

    if constexpr (CSR) {
        __syncthreads();
        float bias2[4];
        #pragma unroll
        for (int nt = 0; nt < 4; ++nt)
            bias2[nt] = load_f(b2, nw + nt * 16 + l15, isf);
        #pragma unroll
        for (int nt = 0; nt < 4; ++nt) {
            int n = nw + nt * 16 + l15;
            #pragma unroll
            for (int mt = 0; mt < 2; ++mt) {
                #pragma unroll
                for (int r = 0; r < 4; ++r) {
                    int mrow = mt * 16 + lq * 4 + r;
                    sA[mrow * LDSF8 + n] = f2fp8(acc[mt][nt][r] + bias2[nt]);
                }
            }
        }
        __syncthreads();
        // stream: 32 rows x 32 uint4 = 1024; 2 per thread
        #pragma unroll
        for (int it = 0; it < 2; ++it) {
            int idx = it * 512 + tid;
            int row = idx >> 5;
            int ch  = idx & 31;
            uint4 v = *(const uint4*)(sA + row * LDSF8 + ch * 16);
            ((uint4*)edgeout)[(blockStart + row) * 32 + ch] = v;
        }
    } else {
        const int half  = wave >> 2;
        const int cbase = nw - half * 256;
        float bias2[4];
        #pragma unroll
        for (int nt = 0; nt < 4; ++nt)
            bias2[nt] = load_f(b2, nw + nt * 16 + l15, isf);
        #pragma unroll
        for (int mt = 0; mt < 2; ++mt) {
            #pragma unroll
            for (int r = 0; r < 4; ++r) {
                int mrow = mt * 16 + lq * 4 + r;
                int   node = sNode[half * ET + mrow];
                float w    = sW[half * ET + mrow];
                float* nrow = numer + (long)node * DD + cbase;
                #pragma unroll
                for (int nt = 0; nt < 4; ++nt)
                    atomicAdd(nrow + nt * 16 + l15, w * (acc[mt][nt][r] + bias2[nt]));
            }
        }
    }
}

// one wave per node: weighted fp8 incidence sum (unroll 8) + inline denom reduce
__global__ __launch_bounds__(256) void node_gather(
    const unsigned* __restrict__ edgeout,   // edge row = 128 uints
    const int* __restrict__ inc,
    const int* __restrict__ offsets,
    const int* __restrict__ count,
    const float* __restrict__ mbuf,
    const void* __restrict__ conf,
    const void* __restrict__ objf,
    void* __restrict__ out,
    const int* __restrict__ flag)
{
    int nid  = blockIdx.x * 4 + (threadIdx.x >> 6);
    if (nid >= O_NODES) return;
    int lane = threadIdx.x & 63;
    int isf  = flag[1];

    int off = offsets[nid];
    int deg = count[nid];
    float mnode = mbuf[nid];

    int j = 0; float wg = 0.f;
    if (lane < deg) {
        j  = inc[off + lane];
        wg = __expf(load_f(conf, j >> 1, isf) - mnode);
    }

    float a0 = 0.f, a1 = 0.f, a2 = 0.f, a3 = 0.f;
    int m  = deg < 64 ? deg : 64;
    int m8 = m & ~7;
    int i = 0;
    for (; i < m8; i += 8) {
        unsigned v[8]; float w[8];
        #pragma unroll
        for (int k = 0; k < 8; ++k) {
            int   jj = __shfl(j, i + k, 64);
            w[k] = __shfl(wg, i + k, 64);
            v[k] = edgeout[(long)(jj >> 1) * 128 + (jj & 1) * 64 + lane];
        }
        #pragma unroll
        for (int k = 0; k < 8; ++k) {
            f32x4 f = unpack4_fp8(v[k]);
            a0 += w[k] * f[0]; a1 += w[k] * f[1]; a2 += w[k] * f[2]; a3 += w[k] * f[3];
        }
    }
    for (; i < m; ++i) {
        int   jj = __shfl(j, i, 64);
        float ww = __shfl(wg, i, 64);
        unsigned v = edgeout[(long)(jj >> 1) * 128 + (jj & 1) * 64 + lane];
        f32x4 f = unpack4_fp8(v);
        a0 += ww * f[0]; a1 += ww * f[1]; a2 += ww * f[2]; a3 += ww * f[3];
    }
    float dtail = 0.f;
    for (int idx = off + 64; idx < off + deg; ++idx) {   // rare deg > 64
        int jj = inc[idx];
        float ww = __expf(load_f(conf, jj >> 1, isf) - mnode);
        dtail += ww;
        unsigned v = edgeout[(long)(jj >> 1) * 128 + (jj & 1) * 64 + lane];
        f32x4 f = unpack4_fp8(v);
        a0 += ww * f[0]; a1 += ww * f[1]; a2 += ww * f[2]; a3 += ww * f[3];
    }

    // inline denom: butterfly-sum the per-lane weights (+ tail, same on all lanes)
    float dsum = wg;
    #pragma unroll
    for (int d = 1; d < 64; d <<= 1) dsum += __shfl_xor(dsum, d, 64);

    float sw  = __expf(10.0f - mnode);
    float inv = 1.0f / (dsum + dtail + sw);
    float o0, o1, o2, o3;
    if (isf) {
        float4 ov = ((const float4*)objf)[(long)nid * 64 + lane];
        o0 = ov.x; o1 = ov.y; o2 = ov.z; o3 = ov.w;
    } else {
        ushort4 ou = ((const ushort4*)objf)[(long)nid * 64 + lane];
        o0 = bf2f(ou.x); o1 = bf2f(ou.y); o2 = bf2f(ou.z); o3 = bf2f(ou.w);
    }
    float r0 = (a0 + sw * o0) * inv;
    float r1 = (a1 + sw * o1) * inv;
    float r2 = (a2 + sw * o2) * inv;
    float r3 = (a3 + sw * o3) * inv;
    if (isf) {
        float4 rv = { r0, r1, r2, r3 };
        ((float4*)out)[(long)nid * 64 + lane] = rv;
    } else {
        __hip_bfloat16 h0 = __float2bfloat16(r0);
        __hip_bfloat16 h1 = __float2bfloat16(r1);
        __hip_bfloat16 h2 = __float2bfloat16(r2);
        __hip_bfloat16 h3 = __float2bfloat16(r3);
        ushort4 ru;
        ru.x = *(unsigned short*)&h0;
        ru.y = *(unsigned short*)&h1;
        ru.z = *(unsigned short*)&h2;
        ru.w = *(unsigned short*)&h3;
        ((ushort4*)out)[(long)nid * 64 + lane] = ru;
    }
}

// fallback finalize (f32 numer)
__global__ void finalize_k(const float* __restrict__ numer, const float* __restrict__ denom,
                           const float* __restrict__ mbuf, const void* __restrict__ objf,
                           void* __restrict__ out, const int* __restrict__ flag) {
    long i4 = (long)blockIdx.x * 256 + threadIdx.x;
    if (i4 >= (long)O_NODES * DD / 4) return;
    int isf = flag[1];
    long base = i4 * 4;
    int node = (int)(base >> 8);
    float sw  = __expf(10.0f - mbuf[node]);
    float inv = 1.0f / (denom[node] + sw);
    f32x4 nm = *(const f32x4*)(numer + base);
    float o0, o1, o2, o3;
    if (isf) {
        float4 ov = ((const float4*)objf)[i4];
        o0 = ov.x; o1 = ov.y; o2 = ov.z; o3 = ov.w;
    } else {
        ushort4 ou = ((const ushort4*)objf)[i4];
        o0 = bf2f(ou.x); o1 = bf2f(ou.y); o2 = bf2f(ou.z); o3 = bf2f(ou.w);
    }
    float r0 = (nm[0] + sw * o0) * inv;
    float r1 = (nm[1] + sw * o1) * inv;
    float r2 = (nm[2] + sw * o2) * inv;
    float r3 = (nm[3] + sw * o3) * inv;
    if (isf) {
        float4 rv = { r0, r1, r2, r3 };
        ((float4*)out)[i4] = rv;
    } else {
        __hip_bfloat16 h0 = __float2bfloat16(r0);
        __hip_bfloat16 h1 = __float2bfloat16(r1);
        __hip_bfloat16 h2 = __float2bfloat16(r2);
        __hip_bfloat16 h3 = __float2bfloat16(r3);
        ushort4 ru;
        ru.x = *(unsigned short*)&h0;
        ru.y = *(unsigned short*)&h1;
        ru.z = *(unsigned short*)&h2;
        ru.w = *(unsigned short*)&h3;
        ((ushort4*)out)[i4] = ru;
    }
}

extern "C" void kernel_launch(void* const* d_in, const int* in_sizes, int n_in,
                              void* d_out, int out_size, void* d_ws, size_t ws_size,
                              hipStream_t stream) {
    const void* objf  = d_in[0];
    const int*  pairs = (const int*)d_in[1];
    const void* conf  = d_in[2];
    const void* W1    = d_in[3];
    const void* b1    = d_in[4];
    const void* W2    = d_in[5];
    const void* b2    = d_in[6];

    const size_t EOUT = (size_t)N_EDGES * 512;             // 102,400,000 B (fp8)
    const size_t OBJ8 = (size_t)O_NODES * DD;              // 12,800,000 B
    const size_t need_csr = EOUT + 200064 + 3 * 200000 + 1600000 + 2 * 262144 + OBJ8;
    char* ws = (char*)d_ws;
    size_t lds = (size_t)ET * LDSF8 + 4 * ET * 4;          // 17408 B

    if (ws_size >= need_csr) {
        unsigned char* edgeout = (unsigned char*)ws;
        int*   count   = (int*)  (ws + EOUT);               // 200000
        int*   flag    = (int*)  (ws + EOUT + 200000);      // 64 (memset with count)
        float* mbuf    = (float*)(ws + EOUT + 200064);
        int*   offsets = (int*)  (ws + EOUT + 400064);
        int*   cursor  = (int*)  (ws + EOUT + 600064);
        int*   inc     = (int*)  (ws + EOUT + 800064);      // 1.6 MB
        unsigned char* w1p = (unsigned char*)(ws + EOUT + 2400064);
        unsigned char* w2p = w1p + 262144;
        unsigned* objf8 = (unsigned*)(w2p + 262144);

        hipMemsetAsync(count, 0, 200064, stream);           // count + flag
        init_all<<<(O_NODES + 255) / 256, 256, 0, stream>>>(pairs, (const unsigned short*)objf, mbuf, flag);
        cvt_objf<<<(O_NODES * DD / 4 + 255) / 256, 256, 0, stream>>>(objf, objf8, flag);
        edge_max_count<<<(N_EDGES + 255) / 256, 256, 0, stream>>>(pairs, conf, mbuf, count, flag);
        scan50k<<<1, SCAN_T, 0, stream>>>(count, offsets, cursor);
        scatter_inc<<<(N_EDGES + 255) / 256, 256, 0, stream>>>(pairs, cursor, inc, flag);
        repack_w2<<<2048, 256, 0, stream>>>(W1, W2, w1p, w2p, flag);

        fused_mlp<1><<<N_EDGES / ET, 512, lds, stream>>>(
            objf8, pairs, conf, w1p, b1, w2p, b2, mbuf, (float*)nullptr, edgeout, flag);

        node_gather<<<(O_NODES + 3) / 4, 256, 0, stream>>>(
            (const unsigned*)edgeout, inc, offsets, count, mbuf, conf, objf, d_out, flag);
    } else {
        float* numer = (float*)ws;
        float* denom = numer + (size_t)O_NODES * DD;
        float* mbuf  = denom + O_NODES;
        int*   count = (int*)(mbuf + O_NODES);
        int*   flag  = count + O_NODES;
        unsigned char* w1p = (unsigned char*)(flag + 16);
        unsigned char* w2p = w1p + 262144;
        unsigned* objf8 = (unsigned*)(w2p + 262144);

        hipMemsetAsync(numer, 0, (size_t)(O_NODES * DD + 2 * O_NODES) * sizeof(float) + 64, stream);
        init_all<<<(O_NODES + 255) / 256, 256, 0, stream>>>(pairs, (const unsigned short*)objf, mbuf, flag);
        cvt_objf<<<(O_NODES * DD / 4 + 255) / 256, 256, 0, stream>>>(objf, objf8, flag);
        edge_max_count<<<(N_EDGES + 255) / 256, 256, 0, stream>>>(pairs, conf, mbuf, count, flag);
        edge_denom<<<(N_EDGES + 255) / 256, 256, 0, stream>>>(pairs, conf, mbuf, denom, flag);
        repack_w2<<<2048, 256, 0, stream>>>(W1, W2, w1p, w2p, flag);

        fused_mlp<0><<<N_EDGES / ET, 512, lds, stream>>>(
            objf8, pairs, conf, w1p, b1, w2p, b2, mbuf, numer, (unsigned char*)nullptr, flag);

        finalize_k<<<(O_NODES * DD / 4 + 255) / 256, 256, 0, stream>>>(numer, denom, mbuf, objf, d_out, flag);
    }
}

// Round 8
// 435.267 us; speedup vs baseline: 1.8477x; 1.1383x over previous
//
#include <hip/hip_runtime.h>
#include <hip/hip_bf16.h>
#include <hip/hip_fp8.h>

#define O_NODES 50000
#define N_EDGES 200000
#define DD 256
#define KDIM 512
#define NDIM 512
#define ET 32           // edges per block

typedef float f32x4 __attribute__((ext_vector_type(4)));

// ---------- fp8 e4m3 helpers ----------
__device__ __forceinline__ unsigned pack4_fp8(float a, float b, float c, float d) {
#if __has_builtin(__builtin_amdgcn_cvt_pk_fp8_f32)
    int v = __builtin_amdgcn_cvt_pk_fp8_f32(a, b, 0, false);
    v = __builtin_amdgcn_cvt_pk_fp8_f32(c, d, v, true);
    return (unsigned)v;
#else
    __hip_fp8_e4m3 x(a), y(b), z(c), w(d);
    return (unsigned)x.__x | ((unsigned)y.__x << 8) | ((unsigned)z.__x << 16) | ((unsigned)w.__x << 24);
#endif
}

__device__ __forceinline__ unsigned char f2fp8(float x) {
#if __has_builtin(__builtin_amdgcn_cvt_pk_fp8_f32)
    return (unsigned char)(__builtin_amdgcn_cvt_pk_fp8_f32(x, x, 0, false) & 0xff);
#else
    __hip_fp8_e4m3 t(x); return t.__x;
#endif
}

__device__ __forceinline__ f32x4 unpack4_fp8(unsigned v) {
#if __has_builtin(__builtin_amdgcn_cvt_pk_f32_fp8)
    auto lo = __builtin_amdgcn_cvt_pk_f32_fp8((int)v, false);
    auto hi = __builtin_amdgcn_cvt_pk_f32_fp8((int)v, true);
    return (f32x4){lo[0], lo[1], hi[0], hi[1]};
#else
    __hip_fp8_e4m3 t0, t1, t2, t3;
    t0.__x = v & 0xff; t1.__x = (v >> 8) & 0xff; t2.__x = (v >> 16) & 0xff; t3.__x = (v >> 24) & 0xff;
    return (f32x4){(float)t0, (float)t1, (float)t2, (float)t3};
#endif
}

__device__ __forceinline__ f32x4 mfma_fp8(long a, long b, f32x4 c) {
    return __builtin_amdgcn_mfma_f32_16x16x32_fp8_fp8(a, b, c, 0, 0, 0);
}

// ---------- generic input helpers ----------
__device__ __forceinline__ int get_pair(const int* __restrict__ p, long e, int which, int is32) {
    return is32 ? p[2 * e + which] : p[4 * e + 2 * which];
}

__device__ __forceinline__ float load_f(const void* p, long i, int is_f32) {
    if (is_f32) return ((const float*)p)[i];
    unsigned short u = ((const unsigned short*)p)[i];
    return __uint_as_float((unsigned)u << 16);
}

__device__ __forceinline__ float bf2f(unsigned short u) {
    return __uint_as_float((unsigned)u << 16);
}

// wave-collective dtype probes (call with full wave active, before any divergence)
__device__ __forceinline__ int detect_is32_w(const int* __restrict__ pairs) {
    int lane = threadIdx.x & 63;
    unsigned long long m = __ballot(pairs[2 * lane + 1] != 0);  // int64 high words all 0
    return m != 0ull;
}
__device__ __forceinline__ int detect_isf_w(const unsigned short* __restrict__ w) {
    int lane = threadIdx.x & 63;
    unsigned short u = w[2 * lane];
    float v = fabsf(__uint_as_float((unsigned)u << 16));
    unsigned long long m = __ballot(v > 0.004f && v < 16.0f);
    return (__popcll(m) < 32) ? 1 : 0;   // low halves mostly out-of-range => f32
}

// ---------- mega setup: cvt_objf | repack W1+W2 (paired layout) | edge max+count | flag ----------
// W pack layout (per matrix, 262144 B): byte idx: j=idx&7, half=(idx>>3)&1, lane=(idx>>4)&63,
// p=(idx>>10)&15, tk=idx>>14 ; holds W[k = tk*32+(lane>>4)*8+j][n = (2p+half)*16+(lane&15)].
// -> ulonglong2 at [(tk*16+p)*64+lane] yields the B-frags for n-tiles (2p, 2p+1).
#define MEGA_A 12500
#define MEGA_B 2048
#define MEGA_C 782
__global__ __launch_bounds__(256) void mega_setup(
    const void* __restrict__ objf, const int* __restrict__ pairs, const void* __restrict__ conf,
    const void* __restrict__ W1, const void* __restrict__ W2,
    unsigned* __restrict__ objf8, unsigned char* __restrict__ w1p, unsigned char* __restrict__ w2p,
    float* __restrict__ mbuf, int* __restrict__ count, int* __restrict__ flag)
{
    int b = blockIdx.x, t = threadIdx.x;
    if (b < MEGA_A) {
        // cvt objf -> fp8 (exact: 12500*256 = 3.2M uints)
        int isf = detect_isf_w((const unsigned short*)objf);
        int i4 = b * 256 + t;
        float x0, x1, x2, x3;
        if (isf) {
            float4 v = ((const float4*)objf)[i4];
            x0 = v.x; x1 = v.y; x2 = v.z; x3 = v.w;
        } else {
            ushort4 u = ((const ushort4*)objf)[i4];
            x0 = bf2f(u.x); x1 = bf2f(u.y); x2 = bf2f(u.z); x3 = bf2f(u.w);
        }
        objf8[i4] = pack4_fp8(x0, x1, x2, x3);
    } else if (b < MEGA_A + MEGA_B) {
        int isf = detect_isf_w((const unsigned short*)objf);
        int bb = b - MEGA_A;
        const void* W = (bb < 1024) ? W1 : W2;
        unsigned char* Wp = (bb < 1024) ? w1p : w2p;
        int idx = ((bb & 1023) << 8) + t;
        int j    = idx & 7;
        int half = (idx >> 3) & 1;
        int lane = (idx >> 4) & 63;
        int p    = (idx >> 10) & 15;
        int tk   = idx >> 14;
        int k = tk * 32 + (lane >> 4) * 8 + j;
        int n = (2 * p + half) * 16 + (lane & 15);
        Wp[idx] = f2fp8(load_f(W, (long)k * NDIM + n, isf));
    } else if (b < MEGA_A + MEGA_B + MEGA_C) {
        int is32 = detect_is32_w(pairs);
        int isf  = detect_isf_w((const unsigned short*)objf);
        int i = (b - MEGA_A - MEGA_B) * 256 + t;
        if (i >= N_EDGES) return;
        int s = get_pair(pairs, i, 0, is32);
        int o = get_pair(pairs, i, 1, is32);
        float c = load_f(conf, i, isf);
        int cb = __float_as_int(c);
        // mbuf memset to 0.0f; negative confs lose to 0 in signed-int max, but all
        // consumers clamp max(mbuf,10) so the result is identical to ref's max(m,10)
        atomicMax((int*)&mbuf[s], cb);
        atomicMax((int*)&mbuf[o], cb);
        atomicAdd(&count[s], 1);
        atomicAdd(&count[o], 1);
    } else {
        // flag block for downstream kernels
        int is32 = detect_is32_w(pairs);
        int isf  = detect_isf_w((const unsigned short*)objf);
        if (t == 0) { flag[0] = is32; flag[1] = isf; }
    }
}

// fallback-only denom (mbuf clamped at read)
__global__ void edge_denom(const int* __restrict__ pairs, const void* __restrict__ conf,
                           const float* __restrict__ mbuf, float* denom, const int* __restrict__ flag) {
    int i = blockIdx.x * 256 + threadIdx.x;
    if (i >= N_EDGES) return;
    int is32 = flag[0], isf = flag[1];
    int s = get_pair(pairs, i, 0, is32);
    int o = get_pair(pairs, i, 1, is32);
    float c = load_f(conf, i, isf);
    atomicAdd(&denom[s], __expf(c - fmaxf(mbuf[s], 10.0f)));
    atomicAdd(&denom[o], __expf(c - fmaxf(mbuf[o], 10.0f)));
}

// coalesced single-block scan
#define SCAN_T 1024
__global__ __launch_bounds__(SCAN_T) void scan50k(const int* __restrict__ count,
                                                  int* __restrict__ offsets,
                                                  int* __restrict__ cursor) {
    __shared__ int wsum[16];
    __shared__ int carry_s;
    int t = threadIdx.x;
    int lane = t & 63, wid = t >> 6;
    if (t == 0) carry_s = 0;
    __syncthreads();
    for (int base = 0; base < O_NODES; base += SCAN_T) {
        int i = base + t;
        int c = (i < O_NODES) ? count[i] : 0;
        int v = c;
        #pragma unroll
        for (int d = 1; d < 64; d <<= 1) {
            int u = __shfl_up(v, d, 64);
            if (lane >= d) v += u;
        }
        if (lane == 63) wsum[wid] = v;
        __syncthreads();
        if (wid == 0) {
            int s = (lane < 16) ? wsum[lane] : 0;
            #pragma unroll
            for (int d = 1; d < 16; d <<= 1) {
                int u = __shfl_up(s, d, 64);
                if (lane >= d) s += u;
            }
            if (lane < 16) wsum[lane] = s;
        }
        __syncthreads();
        int wprefix = (wid == 0) ? 0 : wsum[wid - 1];
        int excl = carry_s + wprefix + v - c;
        if (i < O_NODES) { offsets[i] = excl; cursor[i] = excl; }
        int total = wsum[15];
        __syncthreads();
        if (t == 0) carry_s += total;
        __syncthreads();
    }
}

__global__ void scatter_inc(const int* __restrict__ pairs, int* __restrict__ cursor,
                            int* __restrict__ inc, const int* __restrict__ flag) {
    int i = blockIdx.x * 256 + threadIdx.x;
    if (i >= N_EDGES) return;
    int is32 = flag[0];
    int s = get_pair(pairs, i, 0, is32);
    int o = get_pair(pairs, i, 1, is32);
    int ps = atomicAdd(&cursor[s], 1);
    inc[ps] = 2 * i;
    int po = atomicAdd(&cursor[o], 1);
    inc[po] = 2 * i + 1;
}

// fused MLP. LDS A is stored in MFMA-fragment-major order:
//   frag byte addr = (tk*64 + lane)*16 + mt*8 + j  holds A[m=mt*16+(lane&15)][k=tk*32+(lane>>4)*8+j]
// -> ds_read_b128 at (tk*64+lane)*16 yields both m-tiles' fragments.
// CSR=1: stream UNWEIGHTED fp8 outputs; CSR=0: weighted f32 atomic fallback
template<int CSR>
__global__ __launch_bounds__(512, 4) void fused_mlp(
    const unsigned* __restrict__ objf8,
    const int* __restrict__ pairs,
    const void* __restrict__ conf,
    const unsigned char* __restrict__ w1p,
    const void* __restrict__ b1,
    const unsigned char* __restrict__ w2p,
    const void* __restrict__ b2,
    const float* __restrict__ mbuf,
    float* __restrict__ numer,
    unsigned char* __restrict__ edgeout,
    const int* __restrict__ flag)
{
    extern __shared__ char smem[];
    unsigned char* sA    = (unsigned char*)smem;            // frag: 16KB; row-major epi: 32x528
    int*           sNode = (int*)(smem + 16896);            // [2][ET]
    float*         sW    = (float*)(smem + 16896 + 256);    // [2][ET] (fallback only)

    const int tid  = threadIdx.x;
    const int wave = tid >> 6;      // 0..7
    const int lane = tid & 63;
    const int l15  = lane & 15;
    const int lq   = lane >> 4;
    const long blockStart = (long)blockIdx.x * ET;
    const int is32 = flag[0];
    const int isf  = flag[1];

    if (tid < 2 * ET) {   // 64 threads: one endpoint each
        int which = tid >> 5, ei = tid & 31;
        long e = blockStart + ei;
        int node = get_pair(pairs, e, which, is32);
        sNode[which * ET + ei] = node;
        if constexpr (!CSR) {
            float c = load_f(conf, e, isf);
            sW[which * ET + ei] = __expf(c - fmaxf(mbuf[node], 10.0f));
        }
    }
    __syncthreads();

    // gather: 32 rows x 64 k-octets (8B) = 2048 units; 4 per thread, frag-major dest
    #pragma unroll
    for (int it = 0; it < 4; ++it) {
        int q   = it * 512 + tid;
        int m15 = q & 15;
        int mt  = (q >> 4) & 1;
        int lqk = (q >> 5) & 3;
        int tk  = q >> 7;               // 0..15 ; tk<8 -> sub half, else obj half
        int m   = mt * 16 + m15;
        int node = sNode[(tk >> 3) * ET + m];
        uint2 v = *(const uint2*)(objf8 + (long)node * 64 + (tk & 7) * 8 + lqk * 2);
        *(uint2*)(sA + (tk * 64 + lqk * 16 + m15) * 16 + mt * 8) = v;
    }
    __syncthreads();

    const int nw = wave * 64;
    f32x4 acc[2][4];
    #pragma unroll
    for (int mt = 0; mt < 2; ++mt)
        #pragma unroll
        for (int nt = 0; nt < 4; ++nt)
            acc[mt][nt] = (f32x4){0.f, 0.f, 0.f, 0.f};

    // ---- GEMM1 ----
    {
        const ulonglong2* bq = (const ulonglong2*)w1p;
        #pragma unroll 4
        for (int tk = 0; tk < 16; ++tk) {
            ulonglong2 av  = *(const ulonglong2*)(sA + tk * 1024 + lane * 16);
            ulonglong2 b01 = bq[tk * 1024 + wave * 128 + lane];
            ulonglong2 b23 = bq[tk * 1024 + wave * 128 + 64 + lane];
            long a0 = (long)av.x, a1 = (long)av.y;
            acc[0][0] = mfma_fp8(a0, (long)b01.x, acc[0][0]);
            acc[1][0] = mfma_fp8(a1, (long)b01.x, acc[1][0]);
            acc[0][1] = mfma_fp8(a0, (long)b01.y, acc[0][1]);
            acc[1][1] = mfma_fp8(a1, (long)b01.y, acc[1][1]);
            acc[0][2] = mfma_fp8(a0, (long)b23.x, acc[0][2]);
            acc[1][2] = mfma_fp8(a1, (long)b23.x, acc[1][2]);
            acc[0][3] = mfma_fp8(a0, (long)b23.y, acc[0][3]);
            acc[1][3] = mfma_fp8(a1, (long)b23.y, acc[1][3]);
        }
    }
    __syncthreads();

    // bias + relu -> fp8 h back into sA (frag-major for GEMM2)
    #pragma unroll
    for (int nt = 0; nt < 4; ++nt) {
        int n = nw + nt * 16 + l15;
        float bias = load_f(b1, n, isf);
        int tk2 = wave * 2 + (nt >> 1);
        int lq2 = (nt & 1) * 2 + (l15 >> 3);
        int j   = l15 & 7;
        #pragma unroll
        for (int mt = 0; mt < 2; ++mt) {
            #pragma unroll
            for (int r = 0; r < 4; ++r) {
                int m15 = lq * 4 + r;   // < 16
                sA[(tk2 * 64 + lq2 * 16 + m15) * 16 + mt * 8 + j] =
                    f2fp8(fmaxf(acc[mt][nt][r] + bias, 0.f));
            }
        }
    }
    __syncthreads();

    // ---- GEMM2 ----
    #pragma unroll
    for (int mt = 0; mt < 2; ++mt)
        #pragma unroll
        for (int nt = 0; nt < 4; ++nt)
            acc[mt][nt] = (f32x4){0.f, 0.f, 0.f, 0.f};
    {
        const ulonglong2* bq = (const ulonglong2*)w2p;
        #pragma unroll 4
        for (int tk = 0; tk < 16; ++tk) {
            ulonglong2 av  = *(const ulonglong2*)(sA + tk * 1024 + lane * 16);
            ulonglong2 b01 = bq[tk * 1024 + wave * 128 + lane];
            ulonglong2 b23 = bq[tk * 1024 + wave * 128 + 64 + lane];
            long a0 = (long)av.x, a1 = (long)av.y;
            acc[0][0] = mfma_fp8(a0, (long)b01.x, acc[0][0]);
            acc[1][0] = mfma_fp8(a1, (long)b01.x, acc[1][0]);
            acc[0][1] = mfma_fp8(a0, (long)b01.y, acc[0][1]);
            acc[1][1] = mfma_fp8(a1, (long)b01.y, acc[1][1]);
            acc[0][2] = mfma_fp8(a0, (long)b23.x, acc[0][2]);
            acc[1][2] = mfma_fp8(a1, (long)b23.x, acc[1][2]);
            acc[0][3] = mfma_fp8(a0, (long)b23.y, acc[0][3]);
            acc[1][3] = mfma_fp8(a1, (long)b23.y, acc[1][3]);
        }
    }

    if constexpr (CSR) {
        __syncthreads();
        // out+b2 (fp8) -> row-major sA (stride 528) -> coalesced stream
        #pragma unroll
        for (int nt = 0; nt < 4; ++nt) {
            int n = nw + nt * 16 + l15;
            float bias2 = load_f(b2, n, isf);
            #pragma unroll
            for (int mt = 0; mt < 2; ++mt) {
                #pragma unroll
                for (int r = 0; r < 4; ++r) {
                    int m = mt * 16 + lq * 4 + r;
                    sA[m * 528 + n] = f2fp8(acc[mt][nt][r] + bias2);
                }
            }
        }
        __syncthreads();
        #pragma unroll
        for (int it = 0; it < 2; ++it) {
            int idx = it * 512 + tid;
            int row = idx >> 5;
            int ch  = idx & 31;
            uint4 v = *(const uint4*)(sA + row * 528 + ch * 16);
            ((uint4*)edgeout)[(blockStart + row) * 32 + ch] = v;
        }
    } else {
        const int half  = wave >> 2;
        const int cbase = nw - half * 256;
        #pragma unroll
        for (int nt = 0; nt < 4; ++nt) {
            float bias2 = load_f(b2, nw + nt * 16 + l15, isf);
            #pragma unroll
            for (int mt = 0; mt < 2; ++mt) {
                #pragma unroll
                for (int r = 0; r < 4; ++r) {
                    int mrow = mt * 16 + lq * 4 + r;
                    int   node = sNode[half * ET + mrow];
                    float w    = sW[half * ET + mrow];
                    atomicAdd(numer + (long)node * DD + cbase + nt * 16 + l15,
                              w * (acc[mt][nt][r] + bias2));
                }
            }
        }
    }
}

// one wave per node: weighted fp8 incidence sum (unroll 8) + inline denom reduce
__global__ __launch_bounds__(256) void node_gather(
    const unsigned* __restrict__ edgeout,   // edge row = 128 uints
    const int* __restrict__ inc,
    const int* __restrict__ offsets,
    const int* __restrict__ count,
    const float* __restrict__ mbuf,
    const void* __restrict__ conf,
    const void* __restrict__ objf,
    void* __restrict__ out,
    const int* __restrict__ flag)
{
    int nid  = blockIdx.x * 4 + (threadIdx.x >> 6);
    if (nid >= O_NODES) return;
    int lane = threadIdx.x & 63;
    int isf  = flag[1];

    int off = offsets[nid];
    int deg = count[nid];
    float mnode = fmaxf(mbuf[nid], 10.0f);

    int j = 0; float wg = 0.f;
    if (lane < deg) {
        j  = inc[off + lane];
        wg = __expf(load_f(conf, j >> 1, isf) - mnode);
    }

    float a0 = 0.f, a1 = 0.f, a2 = 0.f, a3 = 0.f;
    int m  = deg < 64 ? deg : 64;
    int m8 = m & ~7;
    int i = 0;
    for (; i < m8; i += 8) {
        unsigned v[8]; float w[8];
        #pragma unroll
        for (int k = 0; k < 8; ++k) {
            int   jj = __shfl(j, i + k, 64);
            w[k] = __shfl(wg, i + k, 64);
            v[k] = edgeout[(long)(jj >> 1) * 128 + (jj & 1) * 64 + lane];
        }
        #pragma unroll
        for (int k = 0; k < 8; ++k) {
            f32x4 f = unpack4_fp8(v[k]);
            a0 += w[k] * f[0]; a1 += w[k] * f[1]; a2 += w[k] * f[2]; a3 += w[k] * f[3];
        }
    }
    for (; i < m; ++i) {
        int   jj = __shfl(j, i, 64);
        float ww = __shfl(wg, i, 64);
        unsigned v = edgeout[(long)(jj >> 1) * 128 + (jj & 1) * 64 + lane];
        f32x4 f = unpack4_fp8(v);
        a0 += ww * f[0]; a1 += ww * f[1]; a2 += ww * f[2]; a3 += ww * f[3];
    }
    float dtail = 0.f;
    for (int idx = off + 64; idx < off + deg; ++idx) {   // rare deg > 64
        int jj = inc[idx];
        float ww = __expf(load_f(conf, jj >> 1, isf) - mnode);
        dtail += ww;
        unsigned v = edgeout[(long)(jj >> 1) * 128 + (jj & 1) * 64 + lane];
        f32x4 f = unpack4_fp8(v);
        a0 += ww * f[0]; a1 += ww * f[1]; a2 += ww * f[2]; a3 += ww * f[3];
    }

    float dsum = wg;
    #pragma unroll
    for (int d = 1; d < 64; d <<= 1) dsum += __shfl_xor(dsum, d, 64);

    float sw  = __expf(10.0f - mnode);
    float inv = 1.0f / (dsum + dtail + sw);
    float o0, o1, o2, o3;
    if (isf) {
        float4 ov = ((const float4*)objf)[(long)nid * 64 + lane];
        o0 = ov.x; o1 = ov.y; o2 = ov.z; o3 = ov.w;
    } else {
        ushort4 ou = ((const ushort4*)objf)[(long)nid * 64 + lane];
        o0 = bf2f(ou.x); o1 = bf2f(ou.y); o2 = bf2f(ou.z); o3 = bf2f(ou.w);
    }
    float r0 = (a0 + sw * o0) * inv;
    float r1 = (a1 + sw * o1) * inv;
    float r2 = (a2 + sw * o2) * inv;
    float r3 = (a3 + sw * o3) * inv;
    if (isf) {
        float4 rv = { r0, r1, r2, r3 };
        ((float4*)out)[(long)nid * 64 + lane] = rv;
    } else {
        __hip_bfloat16 h0 = __float2bfloat16(r0);
        __hip_bfloat16 h1 = __float2bfloat16(r1);
        __hip_bfloat16 h2 = __float2bfloat16(r2);
        __hip_bfloat16 h3 = __float2bfloat16(r3);
        ushort4 ru;
        ru.x = *(unsigned short*)&h0;
        ru.y = *(unsigned short*)&h1;
        ru.z = *(unsigned short*)&h2;
        ru.w = *(unsigned short*)&h3;
        ((ushort4*)out)[(long)nid * 64 + lane] = ru;
    }
}

// fallback finalize (f32 numer)
__global__ void finalize_k(const float* __restrict__ numer, const float* __restrict__ denom,
                           const float* __restrict__ mbuf, const void* __restrict__ objf,
                           void* __restrict__ out, const int* __restrict__ flag) {
    long i4 = (long)blockIdx.x * 256 + threadIdx.x;
    if (i4 >= (long)O_NODES * DD / 4) return;
    int isf = flag[1];
    long base = i4 * 4;
    int node = (int)(base >> 8);
    float sw  = __expf(10.0f - fmaxf(mbuf[node], 10.0f));
    float inv = 1.0f / (denom[node] + sw);
    f32x4 nm = *(const f32x4*)(numer + base);
    float o0, o1, o2, o3;
    if (isf) {
        float4 ov = ((const float4*)objf)[i4];
        o0 = ov.x; o1 = ov.y; o2 = ov.z; o3 = ov.w;
    } else {
        ushort4 ou = ((const ushort4*)objf)[i4];
        o0 = bf2f(ou.x); o1 = bf2f(ou.y); o2 = bf2f(ou.z); o3 = bf2f(ou.w);
    }
    float r0 = (nm[0] + sw * o0) * inv;
    float r1 = (nm[1] + sw * o1) * inv;
    float r2 = (nm[2] + sw * o2) * inv;
    float r3 = (nm[3] + sw * o3) * inv;
    if (isf) {
        float4 rv = { r0, r1, r2, r3 };
        ((float4*)out)[i4] = rv;
    } else {
        __hip_bfloat16 h0 = __float2bfloat16(r0);
        __hip_bfloat16 h1 = __float2bfloat16(r1);
        __hip_bfloat16 h2 = __float2bfloat16(r2);
        __hip_bfloat16 h3 = __float2bfloat16(r3);
        ushort4 ru;
        ru.x = *(unsigned short*)&h0;
        ru.y = *(unsigned short*)&h1;
        ru.z = *(unsigned short*)&h2;
        ru.w = *(unsigned short*)&h3;
        ((ushort4*)out)[i4] = ru;
    }
}

extern "C" void kernel_launch(void* const* d_in, const int* in_sizes, int n_in,
                              void* d_out, int out_size, void* d_ws, size_t ws_size,
                              hipStream_t stream) {
    const void* objf  = d_in[0];
    const int*  pairs = (const int*)d_in[1];
    const void* conf  = d_in[2];
    const void* W1    = d_in[3];
    const void* b1    = d_in[4];
    const void* W2    = d_in[5];
    const void* b2    = d_in[6];

    const size_t EOUT = (size_t)N_EDGES * 512;             // 102,400,000 B (fp8)
    const size_t OBJ8 = (size_t)O_NODES * DD;              // 12,800,000 B
    const size_t need_csr = EOUT + 2400064 + 2 * 262144 + OBJ8;
    char* ws = (char*)d_ws;
    size_t lds = 16896 + 512;                              // 17408 B

    if (ws_size >= need_csr) {
        unsigned char* edgeout = (unsigned char*)ws;
        int*   count   = (int*)  (ws + EOUT);               // 200000
        float* mbuf    = (float*)(ws + EOUT + 200000);      // 200000
        int*   flag    = (int*)  (ws + EOUT + 400000);      // 64
        int*   offsets = (int*)  (ws + EOUT + 400064);
        int*   cursor  = (int*)  (ws + EOUT + 600064);
        int*   inc     = (int*)  (ws + EOUT + 800064);      // 1.6 MB
        unsigned char* w1p = (unsigned char*)(ws + EOUT + 2400064);
        unsigned char* w2p = w1p + 262144;
        unsigned* objf8 = (unsigned*)(w2p + 262144);

        hipMemsetAsync(count, 0, 400064, stream);           // count + mbuf(0) + flag
        mega_setup<<<MEGA_A + MEGA_B + MEGA_C + 1, 256, 0, stream>>>(
            objf, pairs, conf, W1, W2, objf8, w1p, w2p, mbuf, count, flag);
        scan50k<<<1, SCAN_T, 0, stream>>>(count, offsets, cursor);
        scatter_inc<<<(N_EDGES + 255) / 256, 256, 0, stream>>>(pairs, cursor, inc, flag);

        fused_mlp<1><<<N_EDGES / ET, 512, lds, stream>>>(
            objf8, pairs, conf, w1p, b1, w2p, b2, mbuf, (float*)nullptr, edgeout, flag);

        node_gather<<<(O_NODES + 3) / 4, 256, 0, stream>>>(
            (const unsigned*)edgeout, inc, offsets, count, mbuf, conf, objf, d_out, flag);
    } else {
        float* numer = (float*)ws;                              // 51.2 MB
        float* denom = numer + (size_t)O_NODES * DD;
        float* mbuf  = denom + O_NODES;
        int*   count = (int*)(mbuf + O_NODES);
        int*   flag  = count + O_NODES;
        unsigned char* w1p = (unsigned char*)(flag + 16);
        unsigned char* w2p = w1p + 262144;
        unsigned* objf8 = (unsigned*)(w2p + 262144);

        hipMemsetAsync(numer, 0, (size_t)(O_NODES * DD + 3 * O_NODES) * sizeof(float) + 64, stream);
        mega_setup<<<MEGA_A + MEGA_B + MEGA_C + 1, 256, 0, stream>>>(
            objf, pairs, conf, W1, W2, objf8, w1p, w2p, mbuf, count, flag);
        edge_denom<<<(N_EDGES + 255) / 256, 256, 0, stream>>>(pairs, conf, mbuf, denom, flag);

        fused_mlp<0><<<N_EDGES / ET, 512, lds, stream>>>(
            objf8, pairs, conf, w1p, b1, w2p, b2, mbuf, numer, (unsigned char*)nullptr, flag);

        finalize_k<<<(O_NODES * DD / 4 + 255) / 256, 256, 0, stream>>>(numer, denom, mbuf, objf, d_out, flag);
    }
}

// Round 9
// 408.518 us; speedup vs baseline: 1.9686x; 1.0655x over previous
//
#include <hip/hip_runtime.h>
#include <hip/hip_bf16.h>
#include <hip/hip_fp8.h>

#define O_NODES 50000
#define N_EDGES 200000
#define DD 256
#define KDIM 512
#define NDIM 512
#define ET 64           // edges per block

typedef float f32x4 __attribute__((ext_vector_type(4)));

// ---------- fp8 e4m3 helpers ----------
__device__ __forceinline__ unsigned pack4_fp8(float a, float b, float c, float d) {
#if __has_builtin(__builtin_amdgcn_cvt_pk_fp8_f32)
    int v = __builtin_amdgcn_cvt_pk_fp8_f32(a, b, 0, false);
    v = __builtin_amdgcn_cvt_pk_fp8_f32(c, d, v, true);
    return (unsigned)v;
#else
    __hip_fp8_e4m3 x(a), y(b), z(c), w(d);
    return (unsigned)x.__x | ((unsigned)y.__x << 8) | ((unsigned)z.__x << 16) | ((unsigned)w.__x << 24);
#endif
}

__device__ __forceinline__ unsigned char f2fp8(float x) {
#if __has_builtin(__builtin_amdgcn_cvt_pk_fp8_f32)
    return (unsigned char)(__builtin_amdgcn_cvt_pk_fp8_f32(x, x, 0, false) & 0xff);
#else
    __hip_fp8_e4m3 t(x); return t.__x;
#endif
}

__device__ __forceinline__ f32x4 unpack4_fp8(unsigned v) {
#if __has_builtin(__builtin_amdgcn_cvt_pk_f32_fp8)
    auto lo = __builtin_amdgcn_cvt_pk_f32_fp8((int)v, false);
    auto hi = __builtin_amdgcn_cvt_pk_f32_fp8((int)v, true);
    return (f32x4){lo[0], lo[1], hi[0], hi[1]};
#else
    __hip_fp8_e4m3 t0, t1, t2, t3;
    t0.__x = v & 0xff; t1.__x = (v >> 8) & 0xff; t2.__x = (v >> 16) & 0xff; t3.__x = (v >> 24) & 0xff;
    return (f32x4){(float)t0, (float)t1, (float)t2, (float)t3};
#endif
}

__device__ __forceinline__ f32x4 mfma_fp8(long a, long b, f32x4 c) {
    return __builtin_amdgcn_mfma_f32_16x16x32_fp8_fp8(a, b, c, 0, 0, 0);
}

// ---------- generic input helpers ----------
__device__ __forceinline__ int get_pair(const int* __restrict__ p, long e, int which, int is32) {
    return is32 ? p[2 * e + which] : p[4 * e + 2 * which];
}

__device__ __forceinline__ float load_f(const void* p, long i, int is_f32) {
    if (is_f32) return ((const float*)p)[i];
    unsigned short u = ((const unsigned short*)p)[i];
    return __uint_as_float((unsigned)u << 16);
}

__device__ __forceinline__ float bf2f(unsigned short u) {
    return __uint_as_float((unsigned)u << 16);
}

// wave-collective dtype probes (call with full wave active, before any divergence)
__device__ __forceinline__ int detect_is32_w(const int* __restrict__ pairs) {
    int lane = threadIdx.x & 63;
    unsigned long long m = __ballot(pairs[2 * lane + 1] != 0);  // int64 high words all 0
    return m != 0ull;
}
__device__ __forceinline__ int detect_isf_w(const unsigned short* __restrict__ w) {
    int lane = threadIdx.x & 63;
    unsigned short u = w[2 * lane];
    float v = fabsf(__uint_as_float((unsigned)u << 16));
    unsigned long long m = __ballot(v > 0.004f && v < 16.0f);
    return (__popcll(m) < 32) ? 1 : 0;   // low halves mostly out-of-range => f32
}

// ---------- mega setup: cvt_objf | repack W1+W2 (paired layout) | edge max+count | flag ----------
// W pack layout (per matrix, 262144 B): byte idx: j=idx&7, half=(idx>>3)&1, lane=(idx>>4)&63,
// p=(idx>>10)&15, tk=idx>>14 ; holds W[k = tk*32+(lane>>4)*8+j][n = (2p+half)*16+(lane&15)].
// -> ulonglong2 at [(tk*16+p)*64+lane] yields the B-frags for n-tiles (2p, 2p+1).
#define MEGA_A 12500
#define MEGA_B 2048
#define MEGA_C 782
__global__ __launch_bounds__(256) void mega_setup(
    const void* __restrict__ objf, const int* __restrict__ pairs, const void* __restrict__ conf,
    const void* __restrict__ W1, const void* __restrict__ W2,
    unsigned* __restrict__ objf8, unsigned char* __restrict__ w1p, unsigned char* __restrict__ w2p,
    float* __restrict__ mbuf, int* __restrict__ count, int* __restrict__ flag)
{
    int b = blockIdx.x, t = threadIdx.x;
    if (b < MEGA_A) {
        int isf = detect_isf_w((const unsigned short*)objf);
        int i4 = b * 256 + t;
        float x0, x1, x2, x3;
        if (isf) {
            float4 v = ((const float4*)objf)[i4];
            x0 = v.x; x1 = v.y; x2 = v.z; x3 = v.w;
        } else {
            ushort4 u = ((const ushort4*)objf)[i4];
            x0 = bf2f(u.x); x1 = bf2f(u.y); x2 = bf2f(u.z); x3 = bf2f(u.w);
        }
        objf8[i4] = pack4_fp8(x0, x1, x2, x3);
    } else if (b < MEGA_A + MEGA_B) {
        int isf = detect_isf_w((const unsigned short*)objf);
        int bb = b - MEGA_A;
        const void* W = (bb < 1024) ? W1 : W2;
        unsigned char* Wp = (bb < 1024) ? w1p : w2p;
        int idx = ((bb & 1023) << 8) + t;
        int j    = idx & 7;
        int half = (idx >> 3) & 1;
        int lane = (idx >> 4) & 63;
        int p    = (idx >> 10) & 15;
        int tk   = idx >> 14;
        int k = tk * 32 + (lane >> 4) * 8 + j;
        int n = (2 * p + half) * 16 + (lane & 15);
        Wp[idx] = f2fp8(load_f(W, (long)k * NDIM + n, isf));
    } else if (b < MEGA_A + MEGA_B + MEGA_C) {
        int is32 = detect_is32_w(pairs);
        int isf  = detect_isf_w((const unsigned short*)objf);
        int i = (b - MEGA_A - MEGA_B) * 256 + t;
        if (i >= N_EDGES) return;
        int s = get_pair(pairs, i, 0, is32);
        int o = get_pair(pairs, i, 1, is32);
        float c = load_f(conf, i, isf);
        int cb = __float_as_int(c);
        // mbuf memset 0; consumers clamp max(mbuf,10) -> identical to ref max(m,10)
        atomicMax((int*)&mbuf[s], cb);
        atomicMax((int*)&mbuf[o], cb);
        atomicAdd(&count[s], 1);
        atomicAdd(&count[o], 1);
    } else {
        int is32 = detect_is32_w(pairs);
        int isf  = detect_isf_w((const unsigned short*)objf);
        if (t == 0) { flag[0] = is32; flag[1] = isf; }
    }
}

// fallback-only denom (mbuf clamped at read)
__global__ void edge_denom(const int* __restrict__ pairs, const void* __restrict__ conf,
                           const float* __restrict__ mbuf, float* denom, const int* __restrict__ flag) {
    int i = blockIdx.x * 256 + threadIdx.x;
    if (i >= N_EDGES) return;
    int is32 = flag[0], isf = flag[1];
    int s = get_pair(pairs, i, 0, is32);
    int o = get_pair(pairs, i, 1, is32);
    float c = load_f(conf, i, isf);
    atomicAdd(&denom[s], __expf(c - fmaxf(mbuf[s], 10.0f)));
    atomicAdd(&denom[o], __expf(c - fmaxf(mbuf[o], 10.0f)));
}

// coalesced single-block scan
#define SCAN_T 1024
__global__ __launch_bounds__(SCAN_T) void scan50k(const int* __restrict__ count,
                                                  int* __restrict__ offsets,
                                                  int* __restrict__ cursor) {
    __shared__ int wsum[16];
    __shared__ int carry_s;
    int t = threadIdx.x;
    int lane = t & 63, wid = t >> 6;
    if (t == 0) carry_s = 0;
    __syncthreads();
    for (int base = 0; base < O_NODES; base += SCAN_T) {
        int i = base + t;
        int c = (i < O_NODES) ? count[i] : 0;
        int v = c;
        #pragma unroll
        for (int d = 1; d < 64; d <<= 1) {
            int u = __shfl_up(v, d, 64);
            if (lane >= d) v += u;
        }
        if (lane == 63) wsum[wid] = v;
        __syncthreads();
        if (wid == 0) {
            int s = (lane < 16) ? wsum[lane] : 0;
            #pragma unroll
            for (int d = 1; d < 16; d <<= 1) {
                int u = __shfl_up(s, d, 64);
                if (lane >= d) s += u;
            }
            if (lane < 16) wsum[lane] = s;
        }
        __syncthreads();
        int wprefix = (wid == 0) ? 0 : wsum[wid - 1];
        int excl = carry_s + wprefix + v - c;
        if (i < O_NODES) { offsets[i] = excl; cursor[i] = excl; }
        int total = wsum[15];
        __syncthreads();
        if (t == 0) carry_s += total;
        __syncthreads();
    }
}

__global__ void scatter_inc(const int* __restrict__ pairs, int* __restrict__ cursor,
                            int* __restrict__ inc, const int* __restrict__ flag) {
    int i = blockIdx.x * 256 + threadIdx.x;
    if (i >= N_EDGES) return;
    int is32 = flag[0];
    int s = get_pair(pairs, i, 0, is32);
    int o = get_pair(pairs, i, 1, is32);
    int ps = atomicAdd(&cursor[s], 1);
    inc[ps] = 2 * i;
    int po = atomicAdd(&cursor[o], 1);
    inc[po] = 2 * i + 1;
}

// fused MLP, ET=64. A in TWO frag-major 16KB regions (m-tiles 01 / 23):
//   region h byte addr = h*16384 + (tk*64 + lane)*16 + mt'*8 + j
//   holds A[m=(h*2+mt')*16+(lane&15)][k=tk*32+(lane>>4)*8+j]
// -> per tk: 2x ds_read_b128 (contiguous, conflict-free) yield all 4 m-frags.
// CSR=1: stream UNWEIGHTED fp8 outputs; CSR=0: weighted f32 atomic fallback
template<int CSR>
__global__ __launch_bounds__(512, 4) void fused_mlp(
    const unsigned* __restrict__ objf8,
    const int* __restrict__ pairs,
    const void* __restrict__ conf,
    const unsigned char* __restrict__ w1p,
    const void* __restrict__ b1,
    const unsigned char* __restrict__ w2p,
    const void* __restrict__ b2,
    const float* __restrict__ mbuf,
    float* __restrict__ numer,
    unsigned char* __restrict__ edgeout,
    const int* __restrict__ flag)
{
    extern __shared__ char smem[];
    unsigned char* sA    = (unsigned char*)smem;            // frag: 32KB; epi: 64x528 = 33792
    int*           sNode = (int*)(smem + 33792);            // [2][ET]
    float*         sW    = (float*)(smem + 33792 + 512);    // [2][ET] (fallback only)

    const int tid  = threadIdx.x;
    const int wave = tid >> 6;      // 0..7
    const int lane = tid & 63;
    const int l15  = lane & 15;
    const int lq   = lane >> 4;
    const long blockStart = (long)blockIdx.x * ET;
    const int is32 = flag[0];
    const int isf  = flag[1];

    if (tid < 2 * ET) {   // 128 threads: one endpoint each
        int which = tid >> 6, ei = tid & 63;
        long e = blockStart + ei;
        int node = get_pair(pairs, e, which, is32);
        sNode[which * ET + ei] = node;
        if constexpr (!CSR) {
            float c = load_f(conf, e, isf);
            sW[which * ET + ei] = __expf(c - fmaxf(mbuf[node], 10.0f));
        }
    }
    __syncthreads();

    // gather: 64 rows x 64 k-octets = 4096 uint2; 8 per thread, frag-major dest
    #pragma unroll
    for (int it = 0; it < 8; ++it) {
        int q    = it * 512 + tid;
        int m15  = q & 15;
        int mtp  = (q >> 4) & 1;
        int h    = (q >> 5) & 1;
        int lqk  = (q >> 6) & 3;
        int tk   = q >> 8;              // 0..15 ; tk<8 -> sub half, else obj half
        int m    = (h * 2 + mtp) * 16 + m15;
        int node = sNode[(tk >> 3) * ET + m];
        uint2 v = *(const uint2*)(objf8 + (long)node * 64 + (tk & 7) * 8 + lqk * 2);
        *(uint2*)(sA + h * 16384 + (tk * 64 + lqk * 16 + m15) * 16 + mtp * 8) = v;
    }
    __syncthreads();

    const int nw = wave * 64;
    f32x4 acc[4][4];
    #pragma unroll
    for (int mt = 0; mt < 4; ++mt)
        #pragma unroll
        for (int nt = 0; nt < 4; ++nt)
            acc[mt][nt] = (f32x4){0.f, 0.f, 0.f, 0.f};

    // ---- GEMM1 ----
    {
        const ulonglong2* bq = (const ulonglong2*)w1p;
        #pragma unroll 2
        for (int tk = 0; tk < 16; ++tk) {
            ulonglong2 av01 = *(const ulonglong2*)(sA + tk * 1024 + lane * 16);
            ulonglong2 av23 = *(const ulonglong2*)(sA + 16384 + tk * 1024 + lane * 16);
            ulonglong2 b01  = bq[tk * 1024 + wave * 128 + lane];
            ulonglong2 b23  = bq[tk * 1024 + wave * 128 + 64 + lane];
            long a0 = (long)av01.x, a1 = (long)av01.y;
            long a2 = (long)av23.x, a3 = (long)av23.y;
            acc[0][0] = mfma_fp8(a0, (long)b01.x, acc[0][0]);
            acc[1][0] = mfma_fp8(a1, (long)b01.x, acc[1][0]);
            acc[2][0] = mfma_fp8(a2, (long)b01.x, acc[2][0]);
            acc[3][0] = mfma_fp8(a3, (long)b01.x, acc[3][0]);
            acc[0][1] = mfma_fp8(a0, (long)b01.y, acc[0][1]);
            acc[1][1] = mfma_fp8(a1, (long)b01.y, acc[1][1]);
            acc[2][1] = mfma_fp8(a2, (long)b01.y, acc[2][1]);
            acc[3][1] = mfma_fp8(a3, (long)b01.y, acc[3][1]);
            acc[0][2] = mfma_fp8(a0, (long)b23.x, acc[0][2]);
            acc[1][2] = mfma_fp8(a1, (long)b23.x, acc[1][2]);
            acc[2][2] = mfma_fp8(a2, (long)b23.x, acc[2][2]);
            acc[3][2] = mfma_fp8(a3, (long)b23.x, acc[3][2]);
            acc[0][3] = mfma_fp8(a0, (long)b23.y, acc[0][3]);
            acc[1][3] = mfma_fp8(a1, (long)b23.y, acc[1][3]);
            acc[2][3] = mfma_fp8(a2, (long)b23.y, acc[2][3]);
            acc[3][3] = mfma_fp8(a3, (long)b23.y, acc[3][3]);
        }
    }
    __syncthreads();

    // bias + relu -> fp8 h back into sA (frag-major for GEMM2)
    #pragma unroll
    for (int nt = 0; nt < 4; ++nt) {
        int n = nw + nt * 16 + l15;
        float bias = load_f(b1, n, isf);
        int tk2 = wave * 2 + (nt >> 1);
        int lq2 = (nt & 1) * 2 + (l15 >> 3);
        int j   = l15 & 7;
        #pragma unroll
        for (int mt = 0; mt < 4; ++mt) {
            int h   = mt >> 1;
            int mtp = mt & 1;
            #pragma unroll
            for (int r = 0; r < 4; ++r) {
                int m15 = lq * 4 + r;   // < 16
                sA[h * 16384 + (tk2 * 64 + lq2 * 16 + m15) * 16 + mtp * 8 + j] =
                    f2fp8(fmaxf(acc[mt][nt][r] + bias, 0.f));
            }
        }
    }
    __syncthreads();

    // ---- GEMM2 ----
    #pragma unroll
    for (int mt = 0; mt < 4; ++mt)
        #pragma unroll
        for (int nt = 0; nt < 4; ++nt)
            acc[mt][nt] = (f32x4){0.f, 0.f, 0.f, 0.f};
    {
        const ulonglong2* bq = (const ulonglong2*)w2p;
        #pragma unroll 2
        for (int tk = 0; tk < 16; ++tk) {
            ulonglong2 av01 = *(const ulonglong2*)(sA + tk * 1024 + lane * 16);
            ulonglong2 av23 = *(const ulonglong2*)(sA + 16384 + tk * 1024 + lane * 16);
            ulonglong2 b01  = bq[tk * 1024 + wave * 128 + lane];
            ulonglong2 b23  = bq[tk * 1024 + wave * 128 + 64 + lane];
            long a0 = (long)av01.x, a1 = (long)av01.y;
            long a2 = (long)av23.x, a3 = (long)av23.y;
            acc[0][0] = mfma_fp8(a0, (long)b01.x, acc[0][0]);
            acc[1][0] = mfma_fp8(a1, (long)b01.x, acc[1][0]);
            acc[2][0] = mfma_fp8(a2, (long)b01.x, acc[2][0]);
            acc[3][0] = mfma_fp8(a3, (long)b01.x, acc[3][0]);
            acc[0][1] = mfma_fp8(a0, (long)b01.y, acc[0][1]);
            acc[1][1] = mfma_fp8(a1, (long)b01.y, acc[1][1]);
            acc[2][1] = mfma_fp8(a2, (long)b01.y, acc[2][1]);
            acc[3][1] = mfma_fp8(a3, (long)b01.y, acc[3][1]);
            acc[0][2] = mfma_fp8(a0, (long)b23.x, acc[0][2]);
            acc[1][2] = mfma_fp8(a1, (long)b23.x, acc[1][2]);
            acc[2][2] = mfma_fp8(a2, (long)b23.x, acc[2][2]);
            acc[3][2] = mfma_fp8(a3, (long)b23.x, acc[3][2]);
            acc[0][3] = mfma_fp8(a0, (long)b23.y, acc[0][3]);
            acc[1][3] = mfma_fp8(a1, (long)b23.y, acc[1][3]);
            acc[2][3] = mfma_fp8(a2, (long)b23.y, acc[2][3]);
            acc[3][3] = mfma_fp8(a3, (long)b23.y, acc[3][3]);
        }
    }

    if constexpr (CSR) {
        __syncthreads();
        // out+b2 (fp8) -> row-major sA (stride 528) -> coalesced stream
        #pragma unroll
        for (int nt = 0; nt < 4; ++nt) {
            int n = nw + nt * 16 + l15;
            float bias2 = load_f(b2, n, isf);
            #pragma unroll
            for (int mt = 0; mt < 4; ++mt) {
                #pragma unroll
                for (int r = 0; r < 4; ++r) {
                    int m = mt * 16 + lq * 4 + r;
                    sA[m * 528 + n] = f2fp8(acc[mt][nt][r] + bias2);
                }
            }
        }
        __syncthreads();
        // stream: 64 rows x 32 uint4 = 2048; 4 per thread
        #pragma unroll
        for (int it = 0; it < 4; ++it) {
            int idx = it * 512 + tid;
            int row = idx >> 5;
            int ch  = idx & 31;
            uint4 v = *(const uint4*)(sA + row * 528 + ch * 16);
            ((uint4*)edgeout)[(blockStart + row) * 32 + ch] = v;
        }
    } else {
        const int half  = wave >> 2;
        const int cbase = nw - half * 256;
        #pragma unroll
        for (int nt = 0; nt < 4; ++nt) {
            float bias2 = load_f(b2, nw + nt * 16 + l15, isf);
            #pragma unroll
            for (int mt = 0; mt < 4; ++mt) {
                #pragma unroll
                for (int r = 0; r < 4; ++r) {
                    int mrow = mt * 16 + lq * 4 + r;
                    int   node = sNode[half * ET + mrow];
                    float w    = sW[half * ET + mrow];
                    atomicAdd(numer + (long)node * DD + cbase + nt * 16 + l15,
                              w * (acc[mt][nt][r] + bias2));
                }
            }
        }
    }
}

// one wave per node: weighted fp8 incidence sum (unroll 8) + inline denom reduce
__global__ __launch_bounds__(256) void node_gather(
    const unsigned* __restrict__ edgeout,   // edge row = 128 uints
    const int* __restrict__ inc,
    const int* __restrict__ offsets,
    const int* __restrict__ count,
    const float* __restrict__ mbuf,
    const void* __restrict__ conf,
    const void* __restrict__ objf,
    void* __restrict__ out,
    const int* __restrict__ flag)
{
    int nid  = blockIdx.x * 4 + (threadIdx.x >> 6);
    if (nid >= O_NODES) return;
    int lane = threadIdx.x & 63;
    int isf  = flag[1];

    int off = offsets[nid];
    int deg = count[nid];
    float mnode = fmaxf(mbuf[nid], 10.0f);

    int j = 0; float wg = 0.f;
    if (lane < deg) {
        j  = inc[off + lane];
        wg = __expf(load_f(conf, j >> 1, isf) - mnode);
    }

    float a0 = 0.f, a1 = 0.f, a2 = 0.f, a3 = 0.f;
    int m  = deg < 64 ? deg : 64;
    int m8 = m & ~7;
    int i = 0;
    for (; i < m8; i += 8) {
        unsigned v[8]; float w[8];
        #pragma unroll
        for (int k = 0; k < 8; ++k) {
            int   jj = __shfl(j, i + k, 64);
            w[k] = __shfl(wg, i + k, 64);
            v[k] = edgeout[(long)(jj >> 1) * 128 + (jj & 1) * 64 + lane];
        }
        #pragma unroll
        for (int k = 0; k < 8; ++k) {
            f32x4 f = unpack4_fp8(v[k]);
            a0 += w[k] * f[0]; a1 += w[k] * f[1]; a2 += w[k] * f[2]; a3 += w[k] * f[3];
        }
    }
    for (; i < m; ++i) {
        int   jj = __shfl(j, i, 64);
        float ww = __shfl(wg, i, 64);
        unsigned v = edgeout[(long)(jj >> 1) * 128 + (jj & 1) * 64 + lane];
        f32x4 f = unpack4_fp8(v);
        a0 += ww * f[0]; a1 += ww * f[1]; a2 += ww * f[2]; a3 += ww * f[3];
    }
    float dtail = 0.f;
    for (int idx = off + 64; idx < off + deg; ++idx) {   // rare deg > 64
        int jj = inc[idx];
        float ww = __expf(load_f(conf, jj >> 1, isf) - mnode);
        dtail += ww;
        unsigned v = edgeout[(long)(jj >> 1) * 128 + (jj & 1) * 64 + lane];
        f32x4 f = unpack4_fp8(v);
        a0 += ww * f[0]; a1 += ww * f[1]; a2 += ww * f[2]; a3 += ww * f[3];
    }

    float dsum = wg;
    #pragma unroll
    for (int d = 1; d < 64; d <<= 1) dsum += __shfl_xor(dsum, d, 64);

    float sw  = __expf(10.0f - mnode);
    float inv = 1.0f / (dsum + dtail + sw);
    float o0, o1, o2, o3;
    if (isf) {
        float4 ov = ((const float4*)objf)[(long)nid * 64 + lane];
        o0 = ov.x; o1 = ov.y; o2 = ov.z; o3 = ov.w;
    } else {
        ushort4 ou = ((const ushort4*)objf)[(long)nid * 64 + lane];
        o0 = bf2f(ou.x); o1 = bf2f(ou.y); o2 = bf2f(ou.z); o3 = bf2f(ou.w);
    }
    float r0 = (a0 + sw * o0) * inv;
    float r1 = (a1 + sw * o1) * inv;
    float r2 = (a2 + sw * o2) * inv;
    float r3 = (a3 + sw * o3) * inv;
    if (isf) {
        float4 rv = { r0, r1, r2, r3 };
        ((float4*)out)[(long)nid * 64 + lane] = rv;
    } else {
        __hip_bfloat16 h0 = __float2bfloat16(r0);
        __hip_bfloat16 h1 = __float2bfloat16(r1);
        __hip_bfloat16 h2 = __float2bfloat16(r2);
        __hip_bfloat16 h3 = __float2bfloat16(r3);
        ushort4 ru;
        ru.x = *(unsigned short*)&h0;
        ru.y = *(unsigned short*)&h1;
        ru.z = *(unsigned short*)&h2;
        ru.w = *(unsigned short*)&h3;
        ((ushort4*)out)[(long)nid * 64 + lane] = ru;
    }
}

// fallback finalize (f32 numer)
__global__ void finalize_k(const float* __restrict__ numer, const float* __restrict__ denom,
                           const float* __restrict__ mbuf, const void* __restrict__ objf,
                           void* __restrict__ out, const int* __restrict__ flag) {
    long i4 = (long)blockIdx.x * 256 + threadIdx.x;
    if (i4 >= (long)O_NODES * DD / 4) return;
    int isf = flag[1];
    long base = i4 * 4;
    int node = (int)(base >> 8);
    float sw  = __expf(10.0f - fmaxf(mbuf[node], 10.0f));
    float inv = 1.0f / (denom[node] + sw);
    f32x4 nm = *(const f32x4*)(numer + base);
    float o0, o1, o2, o3;
    if (isf) {
        float4 ov = ((const float4*)objf)[i4];
        o0 = ov.x; o1 = ov.y; o2 = ov.z; o3 = ov.w;
    } else {
        ushort4 ou = ((const ushort4*)objf)[i4];
        o0 = bf2f(ou.x); o1 = bf2f(ou.y); o2 = bf2f(ou.z); o3 = bf2f(ou.w);
    }
    float r0 = (nm[0] + sw * o0) * inv;
    float r1 = (nm[1] + sw * o1) * inv;
    float r2 = (nm[2] + sw * o2) * inv;
    float r3 = (nm[3] + sw * o3) * inv;
    if (isf) {
        float4 rv = { r0, r1, r2, r3 };
        ((float4*)out)[i4] = rv;
    } else {
        __hip_bfloat16 h0 = __float2bfloat16(r0);
        __hip_bfloat16 h1 = __float2bfloat16(r1);
        __hip_bfloat16 h2 = __float2bfloat16(r2);
        __hip_bfloat16 h3 = __float2bfloat16(r3);
        ushort4 ru;
        ru.x = *(unsigned short*)&h0;
        ru.y = *(unsigned short*)&h1;
        ru.z = *(unsigned short*)&h2;
        ru.w = *(unsigned short*)&h3;
        ((ushort4*)out)[i4] = ru;
    }
}

extern "C" void kernel_launch(void* const* d_in, const int* in_sizes, int n_in,
                              void* d_out, int out_size, void* d_ws, size_t ws_size,
                              hipStream_t stream) {
    const void* objf  = d_in[0];
    const int*  pairs = (const int*)d_in[1];
    const void* conf  = d_in[2];
    const void* W1    = d_in[3];
    const void* b1    = d_in[4];
    const void* W2    = d_in[5];
    const void* b2    = d_in[6];

    const size_t EOUT = (size_t)N_EDGES * 512;             // 102,400,000 B (fp8)
    const size_t OBJ8 = (size_t)O_NODES * DD;              // 12,800,000 B
    const size_t need_csr = EOUT + 2400064 + 2 * 262144 + OBJ8;
    char* ws = (char*)d_ws;
    size_t lds = 33792 + 512 + 512;                        // 34816 B

    if (ws_size >= need_csr) {
        unsigned char* edgeout = (unsigned char*)ws;
        int*   count   = (int*)  (ws + EOUT);               // 200000
        float* mbuf    = (float*)(ws + EOUT + 200000);      // 200000
        int*   flag    = (int*)  (ws + EOUT + 400000);      // 64
        int*   offsets = (int*)  (ws + EOUT + 400064);
        int*   cursor  = (int*)  (ws + EOUT + 600064);
        int*   inc     = (int*)  (ws + EOUT + 800064);      // 1.6 MB
        unsigned char* w1p = (unsigned char*)(ws + EOUT + 2400064);
        unsigned char* w2p = w1p + 262144;
        unsigned* objf8 = (unsigned*)(w2p + 262144);

        hipMemsetAsync(count, 0, 400064, stream);           // count + mbuf(0) + flag
        mega_setup<<<MEGA_A + MEGA_B + MEGA_C + 1, 256, 0, stream>>>(
            objf, pairs, conf, W1, W2, objf8, w1p, w2p, mbuf, count, flag);
        scan50k<<<1, SCAN_T, 0, stream>>>(count, offsets, cursor);
        scatter_inc<<<(N_EDGES + 255) / 256, 256, 0, stream>>>(pairs, cursor, inc, flag);

        fused_mlp<1><<<N_EDGES / ET, 512, lds, stream>>>(
            objf8, pairs, conf, w1p, b1, w2p, b2, mbuf, (float*)nullptr, edgeout, flag);

        node_gather<<<(O_NODES + 3) / 4, 256, 0, stream>>>(
            (const unsigned*)edgeout, inc, offsets, count, mbuf, conf, objf, d_out, flag);
    } else {
        float* numer = (float*)ws;
        float* denom = numer + (size_t)O_NODES * DD;
        float* mbuf  = denom + O_NODES;
        int*   count = (int*)(mbuf + O_NODES);
        int*   flag  = count + O_NODES;
        unsigned char* w1p = (unsigned char*)(flag + 16);
        unsigned char* w2p = w1p + 262144;
        unsigned* objf8 = (unsigned*)(w2p + 262144);

        hipMemsetAsync(numer, 0, (size_t)(O_NODES * DD + 3 * O_NODES) * sizeof(float) + 64, stream);
        mega_setup<<<MEGA_A + MEGA_B + MEGA_C + 1, 256, 0, stream>>>(
            objf, pairs, conf, W1, W2, objf8, w1p, w2p, mbuf, count, flag);
        edge_denom<<<(N_EDGES + 255) / 256, 256, 0, stream>>>(pairs, conf, mbuf, denom, flag);

        fused_mlp<0><<<N_EDGES / ET, 512, lds, stream>>>(
            objf8, pairs, conf, w1p, b1, w2p, b2, mbuf, numer, (unsigned char*)nullptr, flag);

        finalize_k<<<(O_NODES * DD / 4 + 255) / 256, 256, 0, stream>>>(numer, denom, mbuf, objf, d_out, flag);
    }
}